// Round 13
// baseline (609.857 us; speedup 1.0000x reference)
//
#include <hip/hip_runtime.h>
#include <hip/hip_bf16.h>

#define N_NODES 50000
#define N_PAD 50176        // padded to 3136 row-tiles of 16
#define N_EDGES 500000
#define E2_EDGES 550000    // with self loops appended
#define F_IN 32
#define HEADS 4
#define CH 64
#define HC 256             // HEADS*CH
#define NB 1000
#define NHID 256
#define NOUT 256

static inline int cdiv(long long a, long long b) { return (int)((a + b - 1) / b); }

typedef __bf16 bf16x8 __attribute__((ext_vector_type(8)));
typedef unsigned short us8 __attribute__((ext_vector_type(8)));
typedef unsigned short us4 __attribute__((ext_vector_type(4)));
typedef float f32x4 __attribute__((ext_vector_type(4)));
union BU { us8 u; bf16x8 b; };

// round-to-nearest-even fp32 -> bf16 (bit pattern)
__device__ inline unsigned short f2bf(float f) {
    unsigned u = __float_as_uint(f);
    return (unsigned short)((u + 0x7fffu + ((u >> 16) & 1u)) >> 16);
}
__device__ inline float bf2f(unsigned short h) {
    return __uint_as_float(((unsigned)h) << 16);
}

// ---------- x prep: split fp32 -> hi/lo bf16, A-fragment-major (K=32,NCH=1) --
__global__ void split_frag_kernel(const float* __restrict__ in,
                                  unsigned short* __restrict__ oh,
                                  unsigned short* __restrict__ ol, int n) {
    int i = blockIdx.x * blockDim.x + threadIdx.x;
    if (i >= n * F_IN) return;
    int node = i / F_IN, c = i % F_IN;
    float v = in[i];
    unsigned short hi = f2bf(v);
    size_t dst = (((size_t)(node >> 4)) * 64 + ((c >> 3) & 3) * 16 + (node & 15)) * 8 + (c & 7);
    oh[dst] = hi;
    ol[dst] = f2bf(v - bf2f(hi));
}

// ---------- W prep: split fp32 -> (hi,lo) bf16, B-fragment-major ----------
__global__ void wconv_frag_kernel(const float* __restrict__ W,
                                  unsigned short* __restrict__ Wf_hi,
                                  unsigned short* __restrict__ Wf_lo, int K, int M) {
    int idx = blockIdx.x * blockDim.x + threadIdx.x;
    if (idx >= K * M) return;
    int k = idx / M, m = idx % M;
    float v = W[idx];
    unsigned short hi = f2bf(v);
    unsigned short lo = f2bf(v - bf2f(hi));
    int tcol = m >> 4, l16 = m & 15;
    int ch = k >> 5, quad = (k >> 3) & 3, j = k & 7;
    int NCH = K >> 5;
    size_t dst = ((((size_t)tcol * NCH + ch) * 64) + quad * 16 + l16) * 8 + j;
    Wf_hi[dst] = hi;
    Wf_lo[dst] = lo;
}

// ====== fused split-bf16 MFMA GEMM + attention logits =======================
// h output is written CHANNEL-SLICED: hs[slice=col>>5][node][col&31] so the
// aggregation can run one 32-channel slice per XCD (3.2MB, L2-resident).
template<int K, int M>
__global__ __launch_bounds__(256) void mfma_lin_fused_kernel(
    const unsigned short* __restrict__ Ah, const unsigned short* __restrict__ Al,
    const unsigned short* __restrict__ Wf_hi, const unsigned short* __restrict__ Wf_lo,
    const float* __restrict__ a_src, const float* __restrict__ a_dst,
    unsigned short* __restrict__ Hout, float* __restrict__ als,
    float* __restrict__ ald, int n_rows) {
    constexpr int NCH = K / 32;
    constexpr int CW = M / 64;
    constexpr int RW = 4 / CW;
    constexpr int H_ = M / 64;
    const int wave = threadIdx.x >> 6, lane = threadIdx.x & 63;
    const int quad = lane >> 4, l16 = lane & 15;
    const int head = wave % CW;
    const int col0 = head * 64;
    const int row0 = blockIdx.x * (RW * 64) + (wave / CW) * 64;
    const int rt0 = row0 >> 4;

    f32x4 acc[4][4];
#pragma unroll
    for (int rs = 0; rs < 4; rs++)
#pragma unroll
        for (int t = 0; t < 4; t++) acc[rs][t] = (f32x4){0.f, 0.f, 0.f, 0.f};

    const unsigned short* aph[4];
    const unsigned short* apl[4];
#pragma unroll
    for (int rs = 0; rs < 4; rs++) {
        size_t off = (((size_t)(rt0 + rs) * NCH) * 64 + lane) * 8;
        aph[rs] = Ah + off;
        apl[rs] = Al + off;
    }
    const unsigned short* bh = Wf_hi + ((size_t)(col0 >> 4) * NCH * 64 + lane) * 8;
    const unsigned short* bl = Wf_lo + ((size_t)(col0 >> 4) * NCH * 64 + lane) * 8;

#pragma unroll
    for (int ch = 0; ch < NCH; ch++) {
        BU a_h[4], a_l[4], b_h[4], b_l[4];
#pragma unroll
        for (int rs = 0; rs < 4; rs++) {
            a_h[rs].u = *(const us8*)(aph[rs] + ch * 512);
            a_l[rs].u = *(const us8*)(apl[rs] + ch * 512);
        }
#pragma unroll
        for (int t = 0; t < 4; t++) {
            b_h[t].u = *(const us8*)(bh + (size_t)(t * NCH + ch) * 512);
            b_l[t].u = *(const us8*)(bl + (size_t)(t * NCH + ch) * 512);
        }
#pragma unroll
        for (int t = 0; t < 4; t++) {
#pragma unroll
            for (int rs = 0; rs < 4; rs++) {
                acc[rs][t] = __builtin_amdgcn_mfma_f32_16x16x32_bf16(a_h[rs].b, b_h[t].b, acc[rs][t], 0, 0, 0);
                acc[rs][t] = __builtin_amdgcn_mfma_f32_16x16x32_bf16(a_h[rs].b, b_l[t].b, acc[rs][t], 0, 0, 0);
                acc[rs][t] = __builtin_amdgcn_mfma_f32_16x16x32_bf16(a_l[rs].b, b_h[t].b, acc[rs][t], 0, 0, 0);
            }
        }
    }

    float sv[4], dv[4];
#pragma unroll
    for (int t = 0; t < 4; t++) {
        sv[t] = a_src[col0 + t * 16 + l16];
        dv[t] = a_dst[col0 + t * 16 + l16];
    }
#pragma unroll
    for (int rs = 0; rs < 4; rs++) {
        const int orow0 = row0 + rs * 16 + quad * 4;
#pragma unroll
        for (int i = 0; i < 4; i++) {
            int r = orow0 + i;
            bool ok = (r < n_rows);
            float ps = 0.f, pd = 0.f;
#pragma unroll
            for (int t = 0; t < 4; t++) {
                float v = acc[rs][t][i];
                ps += v * sv[t];
                pd += v * dv[t];
                if (ok) {
                    int col = col0 + t * 16 + l16;
                    Hout[((size_t)(col >> 5) * N_PAD + r) * 32 + (col & 31)] = f2bf(v);
                }
            }
            ps += __shfl_xor(ps, 1);  pd += __shfl_xor(pd, 1);
            ps += __shfl_xor(ps, 2);  pd += __shfl_xor(pd, 2);
            ps += __shfl_xor(ps, 4);  pd += __shfl_xor(pd, 4);
            ps += __shfl_xor(ps, 8);  pd += __shfl_xor(pd, 8);
            if (l16 == 0 && ok) {
                als[r * H_ + head] = ps;
                ald[r * H_ + head] = pd;
            }
        }
    }
}

// ---------- generic small GEMM (MLP layer 1) ----------
template<int K, int M, int TM, int BLOCK, bool RELU>
__global__ __launch_bounds__(BLOCK) void lin_kernel(
    const float* __restrict__ A, const float* __restrict__ W,
    const float* __restrict__ bias, float* __restrict__ C, int n_rows) {
    __shared__ float As[TM][K];
    const int n0 = blockIdx.x * TM;
    const int tid = threadIdx.x;
    for (int idx = tid; idx < TM * K; idx += BLOCK) {
        int r = idx / K, c = idx % K;
        int n = n0 + r;
        As[r][c] = (n < n_rows) ? A[(size_t)n * K + c] : 0.f;
    }
    __syncthreads();
    constexpr int G = BLOCK / M;
    constexpr int RPT = TM / G;
    const int j = tid % M;
    const int g = tid / M;
    float acc[RPT];
#pragma unroll
    for (int i = 0; i < RPT; i++) acc[i] = 0.f;
    for (int k = 0; k < K; k++) {
        float wk = W[(size_t)k * M + j];
#pragma unroll
        for (int i = 0; i < RPT; i++) acc[i] += As[g * RPT + i][k] * wk;
    }
    float bv = bias ? bias[j] : 0.f;
#pragma unroll
    for (int i = 0; i < RPT; i++) {
        int n = n0 + g * RPT + i;
        if (n < n_rows) {
            float v = acc[i] + bv;
            if (RELU) v = fmaxf(v, 0.f);
            C[(size_t)n * M + j] = v;
        }
    }
}

// ======================= CSR build =======================
__global__ void hist_kernel(const int* __restrict__ ei, int* __restrict__ deg) {
    int e = blockIdx.x * blockDim.x + threadIdx.x;
    if (e >= E2_EDGES) return;
    int d = (e < N_EDGES) ? ei[N_EDGES + e] : (e - N_EDGES);
    atomicAdd(deg + d, 1);
}

__global__ __launch_bounds__(256) void scan_block_kernel(const int* __restrict__ deg,
                                                         int* __restrict__ rowptr,
                                                         int* __restrict__ bsum) {
    __shared__ int sdata[256];
    const int b = blockIdx.x, t = threadIdx.x;
    const int base = b * 1024 + t * 4;
    int v[4]; int s = 0;
#pragma unroll
    for (int i = 0; i < 4; i++) {
        int idx = base + i;
        v[i] = (idx < N_NODES) ? deg[idx] : 0;
        s += v[i];
    }
    sdata[t] = s;
    __syncthreads();
    for (int o = 1; o < 256; o <<= 1) {
        int x = (t >= o) ? sdata[t - o] : 0;
        __syncthreads();
        sdata[t] += x;
        __syncthreads();
    }
    if (t == 255) bsum[b] = sdata[255];
    int run = sdata[t] - s;
#pragma unroll
    for (int i = 0; i < 4; i++) {
        int idx = base + i;
        if (idx < N_NODES) rowptr[idx] = run;
        run += v[i];
    }
}

__global__ void scan_bsum_kernel(int* __restrict__ bsum, int nb) {
    if (threadIdx.x == 0 && blockIdx.x == 0) {
        int run = 0;
        for (int i = 0; i < nb; i++) { int v = bsum[i]; bsum[i] = run; run += v; }
    }
}

__global__ void finalize_rowptr_kernel(int* __restrict__ rowptr, const int* __restrict__ bsum,
                                       int* __restrict__ cursor) {
    int i = blockIdx.x * blockDim.x + threadIdx.x;
    if (i >= N_NODES) return;
    int v = rowptr[i] + bsum[i >> 10];
    rowptr[i] = v;
    cursor[i] = v;
}

__global__ void scatter_kernel(const int* __restrict__ ei, int* __restrict__ cursor,
                               int* __restrict__ csr_src) {
    int e = blockIdx.x * blockDim.x + threadIdx.x;
    if (e >= E2_EDGES) return;
    int s, d;
    if (e < N_EDGES) { s = ei[e]; d = ei[N_EDGES + e]; }
    else             { s = d = e - N_EDGES; }
    int pos = atomicAdd(cursor + d, 1);
    csr_src[pos] = s;
}

// ===== XCD-local channel-sliced GAT aggregation ==============================
// slice = blockIdx.x % NSL; with round-robin workgroup->XCD dispatch each
// slice's 3.2MB h working set stays in ONE XCD's private L2 (perf heuristic
// only — correctness is mapping-independent). Wave: 8 edge-slots x 8 lanes;
// each 8-lane group gathers one contiguous 64B slice row per edge; z + acc
// reduced over edge-slots via shfl_xor. No-max softmax (logits bounded O(1)).
// NPW nodes per wave. FRAGOUT: write hi/lo planes in next-GEMM A-frag layout.
template<int NSL, int H_, bool RELU, bool FRAGOUT>
__global__ __launch_bounds__(256) void gat_agg_slice_kernel(
    const int* __restrict__ csr_src, const int* __restrict__ rowptr,
    const int* __restrict__ deg, const unsigned short* __restrict__ hs,
    const float* __restrict__ als, const float* __restrict__ ald,
    const float* __restrict__ bias, unsigned short* __restrict__ outh,
    unsigned short* __restrict__ outl, float* __restrict__ outf, int n) {
    constexpr int NPW = 8;
    const int wave = threadIdx.x >> 6, lane = threadIdx.x & 63;
    const int eg = lane >> 3, cg = lane & 7;
    const int slice = blockIdx.x % NSL;
    const int head = (H_ == 1) ? 0 : (slice >> 1);
    const int base = (blockIdx.x / NSL) * (4 * NPW) + wave * NPW;
    const unsigned short* hsl = hs + (size_t)slice * N_PAD * 32 + cg * 4;
    for (int i = 0; i < NPW; i++) {
        int node = base + i;
        if (node >= n) return;
        const int start = rowptr[node];
        const int len = deg[node];
        const float ad = ald[node * H_ + head];
        float z = 0.f, a0 = 0.f, a1 = 0.f, a2 = 0.f, a3 = 0.f;
        for (int k = eg; k < len; k += 8) {
            int s = csr_src[start + k];
            float x = als[s * H_ + head] + ad;
            x = (x > 0.f) ? x : 0.2f * x;
            float p = __expf(x);
            us4 hv = *(const us4*)(hsl + ((size_t)s << 5));
            z  += p;
            a0 += p * bf2f(hv[0]);
            a1 += p * bf2f(hv[1]);
            a2 += p * bf2f(hv[2]);
            a3 += p * bf2f(hv[3]);
        }
#pragma unroll
        for (int off = 8; off <= 32; off <<= 1) {
            z  += __shfl_xor(z, off);
            a0 += __shfl_xor(a0, off);
            a1 += __shfl_xor(a1, off);
            a2 += __shfl_xor(a2, off);
            a3 += __shfl_xor(a3, off);
        }
        if (eg == 0) {
            float inv = 1.f / (z + 1e-16f);
            int c0 = slice * 32 + cg * 4;
            float vv[4];
            vv[0] = a0 * inv + bias[c0 + 0];
            vv[1] = a1 * inv + bias[c0 + 1];
            vv[2] = a2 * inv + bias[c0 + 2];
            vv[3] = a3 * inv + bias[c0 + 3];
            if (RELU) {
#pragma unroll
                for (int q = 0; q < 4; q++) vv[q] = fmaxf(vv[q], 0.f);
            }
            if (FRAGOUT) {
                us4 vh, vl;
#pragma unroll
                for (int q = 0; q < 4; q++) {
                    unsigned short hi = f2bf(vv[q]);
                    vh[q] = hi;
                    vl[q] = f2bf(vv[q] - bf2f(hi));
                }
                size_t dst = ((((size_t)(node >> 4)) * 8 + slice) * 64
                              + ((cg >> 1) & 3) * 16 + (node & 15)) * 8 + (cg & 1) * 4;
                *(us4*)(outh + dst) = vh;
                *(us4*)(outl + dst) = vl;
            } else {
                *(float4*)(outf + ((size_t)node << 6) + c0) =
                    make_float4(vv[0], vv[1], vv[2], vv[3]);
            }
        }
    }
}

// ---------- mean pooling over (sorted) batch via binary search ----------
__global__ __launch_bounds__(64) void pool_kernel(const float* __restrict__ h3,
                                                  const int* __restrict__ batch,
                                                  float* __restrict__ xg) {
    const int b = blockIdx.x;
    const int j = threadIdx.x;
    int lo = 0, hi = N_NODES;
    while (lo < hi) { int mid = (lo + hi) >> 1; if (batch[mid] < b) lo = mid + 1; else hi = mid; }
    const int start = lo;
    hi = N_NODES;
    while (lo < hi) { int mid = (lo + hi) >> 1; if (batch[mid] < b + 1) lo = mid + 1; else hi = mid; }
    const int end = lo;
    float s = 0.f;
    for (int n = start; n < end; n++) s += h3[(size_t)n * CH + j];
    xg[b * CH + j] = s / fmaxf((float)(end - start), 1.f);
}

// ---------- MLP layer 2 + LayerNorm, one block per graph ----------
__global__ __launch_bounds__(256) void mlp2_ln_kernel(
    const float* __restrict__ y1, const float* __restrict__ Wm2,
    const float* __restrict__ bm2, const float* __restrict__ g2,
    const float* __restrict__ be2, float* __restrict__ out) {
    const int b = blockIdx.x;
    const int j = threadIdx.x;
    __shared__ float yr[NHID];
    yr[j] = y1[(size_t)b * NHID + j];
    __syncthreads();
    float acc = bm2[j];
#pragma unroll 8
    for (int k = 0; k < NHID; k++) acc += yr[k] * Wm2[(size_t)k * NOUT + j];
    float s = acc, s2 = acc * acc;
    for (int o = 32; o > 0; o >>= 1) {
        s += __shfl_down(s, o);
        s2 += __shfl_down(s2, o);
    }
    __shared__ float red[8];
    __shared__ float mv[2];
    int wave = j >> 6, lane = j & 63;
    if (lane == 0) { red[wave] = s; red[4 + wave] = s2; }
    __syncthreads();
    if (j == 0) {
        float ts = red[0] + red[1] + red[2] + red[3];
        float ts2 = red[4] + red[5] + red[6] + red[7];
        float mu = ts / (float)NOUT;
        float var = ts2 / (float)NOUT - mu * mu;
        mv[0] = mu;
        mv[1] = rsqrtf(var + 1e-5f);
    }
    __syncthreads();
    out[(size_t)b * NOUT + j] = (acc - mv[0]) * mv[1] * g2[j] + be2[j];
}

extern "C" void kernel_launch(void* const* d_in, const int* in_sizes, int n_in,
                              void* d_out, int out_size, void* d_ws, size_t ws_size,
                              hipStream_t stream) {
    const float* x      = (const float*)d_in[0];
    const int*   ei     = (const int*)d_in[1];
    const int*   batch  = (const int*)d_in[2];
    const float* W1     = (const float*)d_in[3];
    const float* as1    = (const float*)d_in[4];
    const float* ad1    = (const float*)d_in[5];
    const float* b1     = (const float*)d_in[6];
    const float* W2     = (const float*)d_in[7];
    const float* as2    = (const float*)d_in[8];
    const float* ad2    = (const float*)d_in[9];
    const float* b2     = (const float*)d_in[10];
    const float* W3     = (const float*)d_in[11];
    const float* as3    = (const float*)d_in[12];
    const float* ad3    = (const float*)d_in[13];
    const float* b3     = (const float*)d_in[14];
    const float* Wm1    = (const float*)d_in[15];
    const float* bm1    = (const float*)d_in[16];
    const float* Wm2    = (const float*)d_in[17];
    const float* bm2    = (const float*)d_in[18];
    const float* g2     = (const float*)d_in[19];
    const float* be2    = (const float*)d_in[20];
    float* out = (float*)d_out;

    // workspace layout (bufH sliced: 8 slices x N_PAD x 32)
    unsigned short* bufH = (unsigned short*)d_ws;                  // N_PAD*HC (sliced h)
    unsigned short* aggh = bufH + (size_t)N_PAD * HC;              // N_PAD*HC frag-major
    unsigned short* aggl = aggh + (size_t)N_PAD * HC;              // N_PAD*HC
    unsigned short* xh   = aggl + (size_t)N_PAD * HC;              // N_PAD*F_IN
    unsigned short* xl   = xh + (size_t)N_PAD * F_IN;              // N_PAD*F_IN
    float* bufO3 = (float*)(xl + (size_t)N_PAD * F_IN);            // N*CH fp32
    float* als   = bufO3 + (size_t)N_NODES * CH;                   // N*HEADS
    float* ald   = als + (size_t)N_NODES * HEADS;                  // N*HEADS
    float* xg    = ald + (size_t)N_NODES * HEADS;                  // NB*CH
    float* y1    = xg + (size_t)NB * CH;                           // NB*NHID
    int* deg     = (int*)(y1 + (size_t)NB * NHID);                 // N
    int* rowptr  = deg + N_NODES;                                  // N
    int* cursor  = rowptr + N_NODES;                               // N
    int* bsum    = cursor + N_NODES;                               // <=64
    int* csr_src = bsum + 64;                                      // E2
    unsigned short* wt1h = (unsigned short*)(csr_src + E2_EDGES);  // 256*32
    unsigned short* wt1l = wt1h + 256 * 32;
    unsigned short* wt2h = wt1l + 256 * 32;                        // 256*256
    unsigned short* wt2l = wt2h + 256 * 256;
    unsigned short* wt3h = wt2l + 256 * 256;                       // 64*256
    unsigned short* wt3l = wt3h + 64 * 256;

    const int BLK = 256;
    const int NSCAN = cdiv(N_NODES, 1024);

    // ===================== weight + input prep ==============================
    wconv_frag_kernel<<<cdiv(F_IN * HC, BLK), BLK, 0, stream>>>(W1, wt1h, wt1l, F_IN, HC);
    wconv_frag_kernel<<<cdiv(HC * HC, BLK), BLK, 0, stream>>>(W2, wt2h, wt2l, HC, HC);
    wconv_frag_kernel<<<cdiv(HC * CH, BLK), BLK, 0, stream>>>(W3, wt3h, wt3l, HC, CH);
    split_frag_kernel<<<cdiv(N_NODES * F_IN, BLK), BLK, 0, stream>>>(x, xh, xl, N_NODES);

    // ===================== CSR build (dst-sorted adjacency) ==================
    hipMemsetAsync(deg, 0, (size_t)N_NODES * sizeof(int), stream);
    hist_kernel<<<cdiv(E2_EDGES, BLK), BLK, 0, stream>>>(ei, deg);
    scan_block_kernel<<<NSCAN, 256, 0, stream>>>(deg, rowptr, bsum);
    scan_bsum_kernel<<<1, 64, 0, stream>>>(bsum, NSCAN);
    finalize_rowptr_kernel<<<cdiv(N_NODES, BLK), BLK, 0, stream>>>(rowptr, bsum, cursor);
    scatter_kernel<<<cdiv(E2_EDGES, BLK), BLK, 0, stream>>>(ei, cursor, csr_src);

    // ===================== Layer 1 (F_IN -> H*C) =====================
    mfma_lin_fused_kernel<F_IN, HC><<<cdiv(N_NODES, 64), 256, 0, stream>>>(
        xh, xl, wt1h, wt1l, as1, ad1, bufH, als, ald, N_NODES);
    gat_agg_slice_kernel<8, HEADS, true, true><<<8 * cdiv(N_NODES, 32), 256, 0, stream>>>(
        csr_src, rowptr, deg, bufH, als, ald, b1, aggh, aggl, nullptr, N_NODES);

    // ===================== Layer 2 (H*C -> H*C) =====================
    mfma_lin_fused_kernel<HC, HC><<<cdiv(N_NODES, 64), 256, 0, stream>>>(
        aggh, aggl, wt2h, wt2l, as2, ad2, bufH, als, ald, N_NODES);
    gat_agg_slice_kernel<8, HEADS, true, true><<<8 * cdiv(N_NODES, 32), 256, 0, stream>>>(
        csr_src, rowptr, deg, bufH, als, ald, b2, aggh, aggl, nullptr, N_NODES);

    // ===================== Layer 3 (H*C -> C, heads=1) =====================
    mfma_lin_fused_kernel<HC, CH><<<cdiv(N_NODES, 256), 256, 0, stream>>>(
        aggh, aggl, wt3h, wt3l, as3, ad3, bufH, als, ald, N_NODES);
    gat_agg_slice_kernel<2, 1, false, false><<<2 * cdiv(N_NODES, 32), 256, 0, stream>>>(
        csr_src, rowptr, deg, bufH, als, ald, b3, nullptr, nullptr, bufO3, N_NODES);

    // ===================== Mean pooling (batch is sorted) =====================
    pool_kernel<<<NB, 64, 0, stream>>>(bufO3, batch, xg);

    // ===================== MLP head + LayerNorm =====================
    lin_kernel<CH, NHID, 16, 256, true><<<cdiv(NB, 16), 256, 0, stream>>>(
        xg, Wm1, bm1, y1, NB);
    mlp2_ln_kernel<<<NB, 256, 0, stream>>>(y1, Wm2, bm2, g2, be2, out);
}

// Round 14
// 436.021 us; speedup vs baseline: 1.3987x; 1.3987x over previous
//
#include <hip/hip_runtime.h>
#include <hip/hip_bf16.h>

#define N_NODES 50000
#define N_PAD 50176        // padded to 3136 row-tiles of 16
#define N_EDGES 500000
#define E2_EDGES 550000    // with self loops appended
#define F_IN 32
#define HEADS 4
#define CH 64
#define HC 256             // HEADS*CH
#define NB 1000
#define NHID 256
#define NOUT 256

static inline int cdiv(long long a, long long b) { return (int)((a + b - 1) / b); }

typedef __bf16 bf16x8 __attribute__((ext_vector_type(8)));
typedef unsigned short us8 __attribute__((ext_vector_type(8)));
typedef unsigned short us4 __attribute__((ext_vector_type(4)));
typedef float f32x4 __attribute__((ext_vector_type(4)));
union BU { us8 u; bf16x8 b; };

// round-to-nearest-even fp32 -> bf16 (bit pattern)
__device__ inline unsigned short f2bf(float f) {
    unsigned u = __float_as_uint(f);
    return (unsigned short)((u + 0x7fffu + ((u >> 16) & 1u)) >> 16);
}
__device__ inline float bf2f(unsigned short h) {
    return __uint_as_float(((unsigned)h) << 16);
}

// ---------- x prep: split fp32 -> hi/lo bf16, A-fragment-major (K=32,NCH=1) --
__global__ void split_frag_kernel(const float* __restrict__ in,
                                  unsigned short* __restrict__ oh,
                                  unsigned short* __restrict__ ol, int n) {
    int i = blockIdx.x * blockDim.x + threadIdx.x;
    if (i >= n * F_IN) return;
    int node = i / F_IN, c = i % F_IN;
    float v = in[i];
    unsigned short hi = f2bf(v);
    size_t dst = (((size_t)(node >> 4)) * 64 + ((c >> 3) & 3) * 16 + (node & 15)) * 8 + (c & 7);
    oh[dst] = hi;
    ol[dst] = f2bf(v - bf2f(hi));
}

// ---------- W prep: split fp32 -> (hi,lo) bf16, B-fragment-major ----------
__global__ void wconv_frag_kernel(const float* __restrict__ W,
                                  unsigned short* __restrict__ Wf_hi,
                                  unsigned short* __restrict__ Wf_lo, int K, int M) {
    int idx = blockIdx.x * blockDim.x + threadIdx.x;
    if (idx >= K * M) return;
    int k = idx / M, m = idx % M;
    float v = W[idx];
    unsigned short hi = f2bf(v);
    unsigned short lo = f2bf(v - bf2f(hi));
    int tcol = m >> 4, l16 = m & 15;
    int ch = k >> 5, quad = (k >> 3) & 3, j = k & 7;
    int NCH = K >> 5;
    size_t dst = ((((size_t)tcol * NCH + ch) * 64) + quad * 16 + l16) * 8 + j;
    Wf_hi[dst] = hi;
    Wf_lo[dst] = lo;
}

// ====== fused split-bf16 MFMA GEMM + attention logits (row-major Hout) ======
template<int K, int M>
__global__ __launch_bounds__(256) void mfma_lin_fused_kernel(
    const unsigned short* __restrict__ Ah, const unsigned short* __restrict__ Al,
    const unsigned short* __restrict__ Wf_hi, const unsigned short* __restrict__ Wf_lo,
    const float* __restrict__ a_src, const float* __restrict__ a_dst,
    unsigned short* __restrict__ Hout, float* __restrict__ als,
    float* __restrict__ ald, int n_rows) {
    constexpr int NCH = K / 32;
    constexpr int CW = M / 64;
    constexpr int RW = 4 / CW;
    constexpr int H_ = M / 64;
    const int wave = threadIdx.x >> 6, lane = threadIdx.x & 63;
    const int quad = lane >> 4, l16 = lane & 15;
    const int head = wave % CW;
    const int col0 = head * 64;
    const int row0 = blockIdx.x * (RW * 64) + (wave / CW) * 64;
    const int rt0 = row0 >> 4;

    f32x4 acc[4][4];
#pragma unroll
    for (int rs = 0; rs < 4; rs++)
#pragma unroll
        for (int t = 0; t < 4; t++) acc[rs][t] = (f32x4){0.f, 0.f, 0.f, 0.f};

    const unsigned short* aph[4];
    const unsigned short* apl[4];
#pragma unroll
    for (int rs = 0; rs < 4; rs++) {
        size_t off = (((size_t)(rt0 + rs) * NCH) * 64 + lane) * 8;
        aph[rs] = Ah + off;
        apl[rs] = Al + off;
    }
    const unsigned short* bh = Wf_hi + ((size_t)(col0 >> 4) * NCH * 64 + lane) * 8;
    const unsigned short* bl = Wf_lo + ((size_t)(col0 >> 4) * NCH * 64 + lane) * 8;

#pragma unroll
    for (int ch = 0; ch < NCH; ch++) {
        BU a_h[4], a_l[4], b_h[4], b_l[4];
#pragma unroll
        for (int rs = 0; rs < 4; rs++) {
            a_h[rs].u = *(const us8*)(aph[rs] + ch * 512);
            a_l[rs].u = *(const us8*)(apl[rs] + ch * 512);
        }
#pragma unroll
        for (int t = 0; t < 4; t++) {
            b_h[t].u = *(const us8*)(bh + (size_t)(t * NCH + ch) * 512);
            b_l[t].u = *(const us8*)(bl + (size_t)(t * NCH + ch) * 512);
        }
#pragma unroll
        for (int t = 0; t < 4; t++) {
#pragma unroll
            for (int rs = 0; rs < 4; rs++) {
                acc[rs][t] = __builtin_amdgcn_mfma_f32_16x16x32_bf16(a_h[rs].b, b_h[t].b, acc[rs][t], 0, 0, 0);
                acc[rs][t] = __builtin_amdgcn_mfma_f32_16x16x32_bf16(a_h[rs].b, b_l[t].b, acc[rs][t], 0, 0, 0);
                acc[rs][t] = __builtin_amdgcn_mfma_f32_16x16x32_bf16(a_l[rs].b, b_h[t].b, acc[rs][t], 0, 0, 0);
            }
        }
    }

    float sv[4], dv[4];
#pragma unroll
    for (int t = 0; t < 4; t++) {
        sv[t] = a_src[col0 + t * 16 + l16];
        dv[t] = a_dst[col0 + t * 16 + l16];
    }
#pragma unroll
    for (int rs = 0; rs < 4; rs++) {
        const int orow0 = row0 + rs * 16 + quad * 4;
#pragma unroll
        for (int i = 0; i < 4; i++) {
            int r = orow0 + i;
            bool ok = (r < n_rows);
            float ps = 0.f, pd = 0.f;
#pragma unroll
            for (int t = 0; t < 4; t++) {
                float v = acc[rs][t][i];
                ps += v * sv[t];
                pd += v * dv[t];
                if (ok) Hout[(size_t)r * M + col0 + t * 16 + l16] = f2bf(v);
            }
            ps += __shfl_xor(ps, 1);  pd += __shfl_xor(pd, 1);
            ps += __shfl_xor(ps, 2);  pd += __shfl_xor(pd, 2);
            ps += __shfl_xor(ps, 4);  pd += __shfl_xor(pd, 4);
            ps += __shfl_xor(ps, 8);  pd += __shfl_xor(pd, 8);
            if (l16 == 0 && ok) {
                als[r * H_ + head] = ps;
                ald[r * H_ + head] = pd;
            }
        }
    }
}

// ---------- generic small GEMM (MLP layer 1) ----------
template<int K, int M, int TM, int BLOCK, bool RELU>
__global__ __launch_bounds__(BLOCK) void lin_kernel(
    const float* __restrict__ A, const float* __restrict__ W,
    const float* __restrict__ bias, float* __restrict__ C, int n_rows) {
    __shared__ float As[TM][K];
    const int n0 = blockIdx.x * TM;
    const int tid = threadIdx.x;
    for (int idx = tid; idx < TM * K; idx += BLOCK) {
        int r = idx / K, c = idx % K;
        int n = n0 + r;
        As[r][c] = (n < n_rows) ? A[(size_t)n * K + c] : 0.f;
    }
    __syncthreads();
    constexpr int G = BLOCK / M;
    constexpr int RPT = TM / G;
    const int j = tid % M;
    const int g = tid / M;
    float acc[RPT];
#pragma unroll
    for (int i = 0; i < RPT; i++) acc[i] = 0.f;
    for (int k = 0; k < K; k++) {
        float wk = W[(size_t)k * M + j];
#pragma unroll
        for (int i = 0; i < RPT; i++) acc[i] += As[g * RPT + i][k] * wk;
    }
    float bv = bias ? bias[j] : 0.f;
#pragma unroll
    for (int i = 0; i < RPT; i++) {
        int n = n0 + g * RPT + i;
        if (n < n_rows) {
            float v = acc[i] + bv;
            if (RELU) v = fmaxf(v, 0.f);
            C[(size_t)n * M + j] = v;
        }
    }
}

// ======================= CSR build =======================
__global__ void hist_kernel(const int* __restrict__ ei, int* __restrict__ deg) {
    int e = blockIdx.x * blockDim.x + threadIdx.x;
    if (e >= E2_EDGES) return;
    int d = (e < N_EDGES) ? ei[N_EDGES + e] : (e - N_EDGES);
    atomicAdd(deg + d, 1);
}

__global__ __launch_bounds__(256) void scan_block_kernel(const int* __restrict__ deg,
                                                         int* __restrict__ rowptr,
                                                         int* __restrict__ bsum) {
    __shared__ int sdata[256];
    const int b = blockIdx.x, t = threadIdx.x;
    const int base = b * 1024 + t * 4;
    int v[4]; int s = 0;
#pragma unroll
    for (int i = 0; i < 4; i++) {
        int idx = base + i;
        v[i] = (idx < N_NODES) ? deg[idx] : 0;
        s += v[i];
    }
    sdata[t] = s;
    __syncthreads();
    for (int o = 1; o < 256; o <<= 1) {
        int x = (t >= o) ? sdata[t - o] : 0;
        __syncthreads();
        sdata[t] += x;
        __syncthreads();
    }
    if (t == 255) bsum[b] = sdata[255];
    int run = sdata[t] - s;
#pragma unroll
    for (int i = 0; i < 4; i++) {
        int idx = base + i;
        if (idx < N_NODES) rowptr[idx] = run;
        run += v[i];
    }
}

__global__ void scan_bsum_kernel(int* __restrict__ bsum, int nb) {
    if (threadIdx.x == 0 && blockIdx.x == 0) {
        int run = 0;
        for (int i = 0; i < nb; i++) { int v = bsum[i]; bsum[i] = run; run += v; }
    }
}

__global__ void finalize_rowptr_kernel(int* __restrict__ rowptr, const int* __restrict__ bsum,
                                       int* __restrict__ cursor) {
    int i = blockIdx.x * blockDim.x + threadIdx.x;
    if (i >= N_NODES) return;
    int v = rowptr[i] + bsum[i >> 10];
    rowptr[i] = v;
    cursor[i] = v;
}

__global__ void scatter_kernel(const int* __restrict__ ei, int* __restrict__ cursor,
                               int* __restrict__ csr_src) {
    int e = blockIdx.x * blockDim.x + threadIdx.x;
    if (e >= E2_EDGES) return;
    int s, d;
    if (e < N_EDGES) { s = ei[e]; d = ei[N_EDGES + e]; }
    else             { s = d = e - N_EDGES; }
    int pos = atomicAdd(cursor + d, 1);
    csr_src[pos] = s;
}

// ===== agg v3: half-wave per edge, LDS-staged coalesced frag-major output ====
// Block = 16 nodes (one row-tile); wave w handles 4 nodes. Per edge, a
// half-wave (32 lanes x us8 = full 512B h row) gathers at 16B/lane; halves
// combined via shfl_xor(32). No-max softmax (logits bounded O(1)). Results
// staged in LDS then written frag-major with fully-coalesced 16B stores by
// the whole block (fixes R11's 8B-scatter + cross-XCD partial-line RMW).
__global__ __launch_bounds__(256) void gat_agg_v3_kernel(
    const int* __restrict__ csr_src, const int* __restrict__ rowptr,
    const int* __restrict__ deg, const unsigned short* __restrict__ h,
    const float* __restrict__ als, const float* __restrict__ ald,
    const float* __restrict__ bias, unsigned short* __restrict__ outh,
    unsigned short* __restrict__ outl) {
    constexpr int LP = 264;            // LDS row stride (shorts), 16B-aligned
    __shared__ unsigned short smh[16 * LP];
    __shared__ unsigned short sml[16 * LP];
    const int wave = threadIdx.x >> 6, lane = threadIdx.x & 63;
    const int cl = lane & 31, half = lane >> 5;
    const int head = cl >> 3;          // 8 lanes per head (8 ch each)
    const int rt = blockIdx.x;         // row tile: nodes rt*16 .. rt*16+15
    // bias for this lane's 8 channels (hoisted)
    float bv[8];
#pragma unroll
    for (int i = 0; i < 8; i++) bv[i] = bias[cl * 8 + i];

    for (int nn = 0; nn < 4; nn++) {
        const int node = rt * 16 + wave * 4 + nn;
        const int start = rowptr[node];
        const int len = deg[node];
        const float ad = ald[(node << 2) + head];
        float z = 0.f;
        float a[8];
#pragma unroll
        for (int i = 0; i < 8; i++) a[i] = 0.f;
        const unsigned short* hp = h + cl * 8;
        int k = 0;
        for (; k + 8 <= len; k += 8) {
            int s0 = csr_src[start + k + 0 + half];
            int s1 = csr_src[start + k + 2 + half];
            int s2 = csr_src[start + k + 4 + half];
            int s3 = csr_src[start + k + 6 + half];
            float x0 = als[(s0 << 2) + head] + ad;
            float x1 = als[(s1 << 2) + head] + ad;
            float x2 = als[(s2 << 2) + head] + ad;
            float x3 = als[(s3 << 2) + head] + ad;
            us8 h0 = *(const us8*)(hp + ((size_t)s0 << 8));
            us8 h1 = *(const us8*)(hp + ((size_t)s1 << 8));
            us8 h2 = *(const us8*)(hp + ((size_t)s2 << 8));
            us8 h3 = *(const us8*)(hp + ((size_t)s3 << 8));
            x0 = (x0 > 0.f) ? x0 : 0.2f * x0;
            x1 = (x1 > 0.f) ? x1 : 0.2f * x1;
            x2 = (x2 > 0.f) ? x2 : 0.2f * x2;
            x3 = (x3 > 0.f) ? x3 : 0.2f * x3;
            float p0 = __expf(x0), p1 = __expf(x1);
            float p2 = __expf(x2), p3 = __expf(x3);
            z += p0 + p1 + p2 + p3;
#pragma unroll
            for (int i = 0; i < 8; i++)
                a[i] += p0 * bf2f(h0[i]) + p1 * bf2f(h1[i])
                      + p2 * bf2f(h2[i]) + p3 * bf2f(h3[i]);
        }
        for (; k < len; k += 2) {
            int e = k + half;
            bool valid = (e < len);
            int s0 = csr_src[start + (valid ? e : 0)];
            float x0 = als[(s0 << 2) + head] + ad;
            x0 = (x0 > 0.f) ? x0 : 0.2f * x0;
            float p0 = valid ? __expf(x0) : 0.f;
            us8 h0 = *(const us8*)(hp + ((size_t)s0 << 8));
            z += p0;
#pragma unroll
            for (int i = 0; i < 8; i++) a[i] += p0 * bf2f(h0[i]);
        }
        // combine halves
        z += __shfl_xor(z, 32);
#pragma unroll
        for (int i = 0; i < 8; i++) a[i] += __shfl_xor(a[i], 32);
        if (half == 0) {
            float inv = 1.f / (z + 1e-16f);
            us8 vh, vl;
#pragma unroll
            for (int i = 0; i < 8; i++) {
                float v = fmaxf(a[i] * inv + bv[i], 0.f);   // relu (layers 1,2)
                unsigned short hi = f2bf(v);
                vh[i] = hi;
                vl[i] = f2bf(v - bf2f(hi));
            }
            int nl = wave * 4 + nn;     // node&15
            *(us8*)(smh + nl * LP + cl * 8) = vh;
            *(us8*)(sml + nl * LP + cl * 8) = vl;
        }
    }
    __syncthreads();
    // cooperative coalesced frag-major write: 8 chunks x 64 lanes x 16B
#pragma unroll
    for (int f = threadIdx.x; f < 512; f += 256) {
        int chunk = f >> 6, ln = f & 63;
        int quad = ln >> 4, l16 = ln & 15;
        us8 vh = *(const us8*)(smh + l16 * LP + chunk * 32 + quad * 8);
        us8 vl = *(const us8*)(sml + l16 * LP + chunk * 32 + quad * 8);
        size_t dst = (((size_t)rt * 8 + chunk) * 64 + ln) * 8;
        *(us8*)(outh + dst) = vh;
        *(us8*)(outl + dst) = vl;
    }
}

// ===== layer-3 agg: H=1, C=64, no-max softmax, fp32 out =====
__global__ __launch_bounds__(256) void gat_agg_h1_kernel(
    const int* __restrict__ csr_src, const int* __restrict__ rowptr,
    const int* __restrict__ deg, const unsigned short* __restrict__ h,
    const float* __restrict__ als, const float* __restrict__ ald,
    const float* __restrict__ bias, float* __restrict__ out, int n) {
    const int lane = threadIdx.x & 63;
    const int node = (blockIdx.x << 2) + (threadIdx.x >> 6);
    if (node >= n) return;
    const int start = rowptr[node];
    const int len = deg[node];
    const float ad = ald[node];
    float z = 0.f, acc = 0.f;
    int k = 0;
    for (; k + 4 <= len; k += 4) {
        int s0 = csr_src[start + k + 0];
        int s1 = csr_src[start + k + 1];
        int s2 = csr_src[start + k + 2];
        int s3 = csr_src[start + k + 3];
        float a0 = als[s0], a1 = als[s1], a2 = als[s2], a3 = als[s3];
        float h0 = bf2f(h[((size_t)s0 << 6) + lane]);
        float h1 = bf2f(h[((size_t)s1 << 6) + lane]);
        float h2 = bf2f(h[((size_t)s2 << 6) + lane]);
        float h3 = bf2f(h[((size_t)s3 << 6) + lane]);
        float x0 = a0 + ad; x0 = (x0 > 0.f) ? x0 : 0.2f * x0;
        float x1 = a1 + ad; x1 = (x1 > 0.f) ? x1 : 0.2f * x1;
        float x2 = a2 + ad; x2 = (x2 > 0.f) ? x2 : 0.2f * x2;
        float x3 = a3 + ad; x3 = (x3 > 0.f) ? x3 : 0.2f * x3;
        float p0 = __expf(x0), p1 = __expf(x1);
        float p2 = __expf(x2), p3 = __expf(x3);
        z += p0 + p1 + p2 + p3;
        acc += p0 * h0 + p1 * h1 + p2 * h2 + p3 * h3;
    }
    for (; k < len; k++) {
        int s0 = csr_src[start + k];
        float x0 = als[s0] + ad; x0 = (x0 > 0.f) ? x0 : 0.2f * x0;
        float h0 = bf2f(h[((size_t)s0 << 6) + lane]);
        float p0 = __expf(x0);
        z += p0;
        acc += p0 * h0;
    }
    out[((size_t)node << 6) + lane] = acc / (z + 1e-16f) + bias[lane];
}

// ---------- mean pooling over (sorted) batch via binary search ----------
__global__ __launch_bounds__(64) void pool_kernel(const float* __restrict__ h3,
                                                  const int* __restrict__ batch,
                                                  float* __restrict__ xg) {
    const int b = blockIdx.x;
    const int j = threadIdx.x;
    int lo = 0, hi = N_NODES;
    while (lo < hi) { int mid = (lo + hi) >> 1; if (batch[mid] < b) lo = mid + 1; else hi = mid; }
    const int start = lo;
    hi = N_NODES;
    while (lo < hi) { int mid = (lo + hi) >> 1; if (batch[mid] < b + 1) lo = mid + 1; else hi = mid; }
    const int end = lo;
    float s = 0.f;
    for (int n = start; n < end; n++) s += h3[(size_t)n * CH + j];
    xg[b * CH + j] = s / fmaxf((float)(end - start), 1.f);
}

// ---------- MLP layer 2 + LayerNorm, one block per graph ----------
__global__ __launch_bounds__(256) void mlp2_ln_kernel(
    const float* __restrict__ y1, const float* __restrict__ Wm2,
    const float* __restrict__ bm2, const float* __restrict__ g2,
    const float* __restrict__ be2, float* __restrict__ out) {
    const int b = blockIdx.x;
    const int j = threadIdx.x;
    __shared__ float yr[NHID];
    yr[j] = y1[(size_t)b * NHID + j];
    __syncthreads();
    float acc = bm2[j];
#pragma unroll 8
    for (int k = 0; k < NHID; k++) acc += yr[k] * Wm2[(size_t)k * NOUT + j];
    float s = acc, s2 = acc * acc;
    for (int o = 32; o > 0; o >>= 1) {
        s += __shfl_down(s, o);
        s2 += __shfl_down(s2, o);
    }
    __shared__ float red[8];
    __shared__ float mv[2];
    int wave = j >> 6, lane = j & 63;
    if (lane == 0) { red[wave] = s; red[4 + wave] = s2; }
    __syncthreads();
    if (j == 0) {
        float ts = red[0] + red[1] + red[2] + red[3];
        float ts2 = red[4] + red[5] + red[6] + red[7];
        float mu = ts / (float)NOUT;
        float var = ts2 / (float)NOUT - mu * mu;
        mv[0] = mu;
        mv[1] = rsqrtf(var + 1e-5f);
    }
    __syncthreads();
    out[(size_t)b * NOUT + j] = (acc - mv[0]) * mv[1] * g2[j] + be2[j];
}

extern "C" void kernel_launch(void* const* d_in, const int* in_sizes, int n_in,
                              void* d_out, int out_size, void* d_ws, size_t ws_size,
                              hipStream_t stream) {
    const float* x      = (const float*)d_in[0];
    const int*   ei     = (const int*)d_in[1];
    const int*   batch  = (const int*)d_in[2];
    const float* W1     = (const float*)d_in[3];
    const float* as1    = (const float*)d_in[4];
    const float* ad1    = (const float*)d_in[5];
    const float* b1     = (const float*)d_in[6];
    const float* W2     = (const float*)d_in[7];
    const float* as2    = (const float*)d_in[8];
    const float* ad2    = (const float*)d_in[9];
    const float* b2     = (const float*)d_in[10];
    const float* W3     = (const float*)d_in[11];
    const float* as3    = (const float*)d_in[12];
    const float* ad3    = (const float*)d_in[13];
    const float* b3     = (const float*)d_in[14];
    const float* Wm1    = (const float*)d_in[15];
    const float* bm1    = (const float*)d_in[16];
    const float* Wm2    = (const float*)d_in[17];
    const float* bm2    = (const float*)d_in[18];
    const float* g2     = (const float*)d_in[19];
    const float* be2    = (const float*)d_in[20];
    float* out = (float*)d_out;

    // workspace layout (A-plane buffers padded to N_PAD rows)
    unsigned short* bufH = (unsigned short*)d_ws;                  // N*HC bf16 (row-major h)
    unsigned short* aggh = bufH + (size_t)N_NODES * HC;            // N_PAD*HC frag-major
    unsigned short* aggl = aggh + (size_t)N_PAD * HC;              // N_PAD*HC
    unsigned short* xh   = aggl + (size_t)N_PAD * HC;              // N_PAD*F_IN
    unsigned short* xl   = xh + (size_t)N_PAD * F_IN;              // N_PAD*F_IN
    float* bufO3 = (float*)(xl + (size_t)N_PAD * F_IN);            // N*CH fp32
    float* als   = bufO3 + (size_t)N_NODES * CH;                   // N*HEADS
    float* ald   = als + (size_t)N_NODES * HEADS;                  // N*HEADS
    float* xg    = ald + (size_t)N_NODES * HEADS;                  // NB*CH
    float* y1    = xg + (size_t)NB * CH;                           // NB*NHID
    int* deg     = (int*)(y1 + (size_t)NB * NHID);                 // N
    int* rowptr  = deg + N_NODES;                                  // N
    int* cursor  = rowptr + N_NODES;                               // N
    int* bsum    = cursor + N_NODES;                               // <=64
    int* csr_src = bsum + 64;                                      // E2
    unsigned short* wt1h = (unsigned short*)(csr_src + E2_EDGES);  // 256*32
    unsigned short* wt1l = wt1h + 256 * 32;
    unsigned short* wt2h = wt1l + 256 * 32;                        // 256*256
    unsigned short* wt2l = wt2h + 256 * 256;
    unsigned short* wt3h = wt2l + 256 * 256;                       // 64*256
    unsigned short* wt3l = wt3h + 64 * 256;

    const int BLK = 256;
    const int NSCAN = cdiv(N_NODES, 1024);

    // ===================== weight + input prep ==============================
    wconv_frag_kernel<<<cdiv(F_IN * HC, BLK), BLK, 0, stream>>>(W1, wt1h, wt1l, F_IN, HC);
    wconv_frag_kernel<<<cdiv(HC * HC, BLK), BLK, 0, stream>>>(W2, wt2h, wt2l, HC, HC);
    wconv_frag_kernel<<<cdiv(HC * CH, BLK), BLK, 0, stream>>>(W3, wt3h, wt3l, HC, CH);
    split_frag_kernel<<<cdiv(N_NODES * F_IN, BLK), BLK, 0, stream>>>(x, xh, xl, N_NODES);

    // ===================== CSR build (dst-sorted adjacency) ==================
    hipMemsetAsync(deg, 0, (size_t)N_NODES * sizeof(int), stream);
    hist_kernel<<<cdiv(E2_EDGES, BLK), BLK, 0, stream>>>(ei, deg);
    scan_block_kernel<<<NSCAN, 256, 0, stream>>>(deg, rowptr, bsum);
    scan_bsum_kernel<<<1, 64, 0, stream>>>(bsum, NSCAN);
    finalize_rowptr_kernel<<<cdiv(N_NODES, BLK), BLK, 0, stream>>>(rowptr, bsum, cursor);
    scatter_kernel<<<cdiv(E2_EDGES, BLK), BLK, 0, stream>>>(ei, cursor, csr_src);

    // ===================== Layer 1 (F_IN -> H*C) =====================
    mfma_lin_fused_kernel<F_IN, HC><<<cdiv(N_NODES, 64), 256, 0, stream>>>(
        xh, xl, wt1h, wt1l, as1, ad1, bufH, als, ald, N_NODES);
    gat_agg_v3_kernel<<<N_NODES / 16, 256, 0, stream>>>(
        csr_src, rowptr, deg, bufH, als, ald, b1, aggh, aggl);

    // ===================== Layer 2 (H*C -> H*C) =====================
    mfma_lin_fused_kernel<HC, HC><<<cdiv(N_NODES, 64), 256, 0, stream>>>(
        aggh, aggl, wt2h, wt2l, as2, ad2, bufH, als, ald, N_NODES);
    gat_agg_v3_kernel<<<N_NODES / 16, 256, 0, stream>>>(
        csr_src, rowptr, deg, bufH, als, ald, b2, aggh, aggl);

    // ===================== Layer 3 (H*C -> C, heads=1) =====================
    mfma_lin_fused_kernel<HC, CH><<<cdiv(N_NODES, 256), 256, 0, stream>>>(
        aggh, aggl, wt3h, wt3l, as3, ad3, bufH, als, ald, N_NODES);
    gat_agg_h1_kernel<<<cdiv(N_NODES, 4), 256, 0, stream>>>(
        csr_src, rowptr, deg, bufH, als, ald, b3, bufO3, N_NODES);

    // ===================== Mean pooling (batch is sorted) =====================
    pool_kernel<<<NB, 64, 0, stream>>>(bufO3, batch, xg);

    // ===================== MLP head + LayerNorm =====================
    lin_kernel<CH, NHID, 16, 256, true><<<cdiv(NB, 16), 256, 0, stream>>>(
        xg, Wm1, bm1, y1, NB);
    mlp2_ln_kernel<<<NB, 256, 0, stream>>>(y1, Wm2, bm2, g2, be2, out);
}

// Round 15
// 411.727 us; speedup vs baseline: 1.4812x; 1.0590x over previous
//
#include <hip/hip_runtime.h>
#include <hip/hip_bf16.h>

#define N_NODES 50000
#define N_PAD 50176        // padded to 3136 row-tiles of 16
#define N_EDGES 500000
#define E2_EDGES 550000    // with self loops appended
#define F_IN 32
#define HEADS 4
#define CH 64
#define HC 256             // HEADS*CH
#define NB 1000
#define NHID 256
#define NOUT 256

static inline int cdiv(long long a, long long b) { return (int)((a + b - 1) / b); }

typedef __bf16 bf16x8 __attribute__((ext_vector_type(8)));
typedef unsigned short us8 __attribute__((ext_vector_type(8)));
typedef unsigned short us4 __attribute__((ext_vector_type(4)));
typedef float f32x4 __attribute__((ext_vector_type(4)));
union BU { us8 u; bf16x8 b; };

// round-to-nearest-even fp32 -> bf16 (bit pattern)
__device__ inline unsigned short f2bf(float f) {
    unsigned u = __float_as_uint(f);
    return (unsigned short)((u + 0x7fffu + ((u >> 16) & 1u)) >> 16);
}
__device__ inline float bf2f(unsigned short h) {
    return __uint_as_float(((unsigned)h) << 16);
}

// ---------- x prep: split fp32 -> hi/lo bf16, A-fragment-major (K=32,NCH=1) --
__global__ void split_frag_kernel(const float* __restrict__ in,
                                  unsigned short* __restrict__ oh,
                                  unsigned short* __restrict__ ol, int n) {
    int i = blockIdx.x * blockDim.x + threadIdx.x;
    if (i >= n * F_IN) return;
    int node = i / F_IN, c = i % F_IN;
    float v = in[i];
    unsigned short hi = f2bf(v);
    size_t dst = (((size_t)(node >> 4)) * 64 + ((c >> 3) & 3) * 16 + (node & 15)) * 8 + (c & 7);
    oh[dst] = hi;
    ol[dst] = f2bf(v - bf2f(hi));
}

// ---------- W prep: split fp32 -> (hi,lo) bf16, B-fragment-major ----------
__global__ void wconv_frag_kernel(const float* __restrict__ W,
                                  unsigned short* __restrict__ Wf_hi,
                                  unsigned short* __restrict__ Wf_lo, int K, int M) {
    int idx = blockIdx.x * blockDim.x + threadIdx.x;
    if (idx >= K * M) return;
    int k = idx / M, m = idx % M;
    float v = W[idx];
    unsigned short hi = f2bf(v);
    unsigned short lo = f2bf(v - bf2f(hi));
    int tcol = m >> 4, l16 = m & 15;
    int ch = k >> 5, quad = (k >> 3) & 3, j = k & 7;
    int NCH = K >> 5;
    size_t dst = ((((size_t)tcol * NCH + ch) * 64) + quad * 16 + l16) * 8 + j;
    Wf_hi[dst] = hi;
    Wf_lo[dst] = lo;
}

// ====== fused split-bf16 MFMA GEMM + attention logits (row-major Hout) ======
// ALO: A has a lo plane (3-term split). For agg outputs A is plain bf16
// (2-term: ah*bh + ah*bl) — A-side 0.2% rel err, invisible at our margin.
template<int K, int M, bool ALO>
__global__ __launch_bounds__(256) void mfma_lin_fused_kernel(
    const unsigned short* __restrict__ Ah, const unsigned short* __restrict__ Al,
    const unsigned short* __restrict__ Wf_hi, const unsigned short* __restrict__ Wf_lo,
    const float* __restrict__ a_src, const float* __restrict__ a_dst,
    unsigned short* __restrict__ Hout, float* __restrict__ als,
    float* __restrict__ ald, int n_rows) {
    constexpr int NCH = K / 32;
    constexpr int CW = M / 64;
    constexpr int RW = 4 / CW;
    constexpr int H_ = M / 64;
    const int wave = threadIdx.x >> 6, lane = threadIdx.x & 63;
    const int quad = lane >> 4, l16 = lane & 15;
    const int head = wave % CW;
    const int col0 = head * 64;
    const int row0 = blockIdx.x * (RW * 64) + (wave / CW) * 64;
    const int rt0 = row0 >> 4;

    f32x4 acc[4][4];
#pragma unroll
    for (int rs = 0; rs < 4; rs++)
#pragma unroll
        for (int t = 0; t < 4; t++) acc[rs][t] = (f32x4){0.f, 0.f, 0.f, 0.f};

    const unsigned short* aph[4];
    const unsigned short* apl[4];
#pragma unroll
    for (int rs = 0; rs < 4; rs++) {
        size_t off = (((size_t)(rt0 + rs) * NCH) * 64 + lane) * 8;
        aph[rs] = Ah + off;
        if (ALO) apl[rs] = Al + off;
    }
    const unsigned short* bh = Wf_hi + ((size_t)(col0 >> 4) * NCH * 64 + lane) * 8;
    const unsigned short* bl = Wf_lo + ((size_t)(col0 >> 4) * NCH * 64 + lane) * 8;

#pragma unroll
    for (int ch = 0; ch < NCH; ch++) {
        BU a_h[4], a_l[4], b_h[4], b_l[4];
#pragma unroll
        for (int rs = 0; rs < 4; rs++) {
            a_h[rs].u = *(const us8*)(aph[rs] + ch * 512);
            if (ALO) a_l[rs].u = *(const us8*)(apl[rs] + ch * 512);
        }
#pragma unroll
        for (int t = 0; t < 4; t++) {
            b_h[t].u = *(const us8*)(bh + (size_t)(t * NCH + ch) * 512);
            b_l[t].u = *(const us8*)(bl + (size_t)(t * NCH + ch) * 512);
        }
#pragma unroll
        for (int t = 0; t < 4; t++) {
#pragma unroll
            for (int rs = 0; rs < 4; rs++) {
                acc[rs][t] = __builtin_amdgcn_mfma_f32_16x16x32_bf16(a_h[rs].b, b_h[t].b, acc[rs][t], 0, 0, 0);
                acc[rs][t] = __builtin_amdgcn_mfma_f32_16x16x32_bf16(a_h[rs].b, b_l[t].b, acc[rs][t], 0, 0, 0);
                if (ALO)
                    acc[rs][t] = __builtin_amdgcn_mfma_f32_16x16x32_bf16(a_l[rs].b, b_h[t].b, acc[rs][t], 0, 0, 0);
            }
        }
    }

    float sv[4], dv[4];
#pragma unroll
    for (int t = 0; t < 4; t++) {
        sv[t] = a_src[col0 + t * 16 + l16];
        dv[t] = a_dst[col0 + t * 16 + l16];
    }
#pragma unroll
    for (int rs = 0; rs < 4; rs++) {
        const int orow0 = row0 + rs * 16 + quad * 4;
#pragma unroll
        for (int i = 0; i < 4; i++) {
            int r = orow0 + i;
            bool ok = (r < n_rows);
            float ps = 0.f, pd = 0.f;
#pragma unroll
            for (int t = 0; t < 4; t++) {
                float v = acc[rs][t][i];
                ps += v * sv[t];
                pd += v * dv[t];
                if (ok) Hout[(size_t)r * M + col0 + t * 16 + l16] = f2bf(v);
            }
            ps += __shfl_xor(ps, 1);  pd += __shfl_xor(pd, 1);
            ps += __shfl_xor(ps, 2);  pd += __shfl_xor(pd, 2);
            ps += __shfl_xor(ps, 4);  pd += __shfl_xor(pd, 4);
            ps += __shfl_xor(ps, 8);  pd += __shfl_xor(pd, 8);
            if (l16 == 0 && ok) {
                als[r * H_ + head] = ps;
                ald[r * H_ + head] = pd;
            }
        }
    }
}

// ---------- generic small GEMM (MLP layer 1) ----------
template<int K, int M, int TM, int BLOCK, bool RELU>
__global__ __launch_bounds__(BLOCK) void lin_kernel(
    const float* __restrict__ A, const float* __restrict__ W,
    const float* __restrict__ bias, float* __restrict__ C, int n_rows) {
    __shared__ float As[TM][K];
    const int n0 = blockIdx.x * TM;
    const int tid = threadIdx.x;
    for (int idx = tid; idx < TM * K; idx += BLOCK) {
        int r = idx / K, c = idx % K;
        int n = n0 + r;
        As[r][c] = (n < n_rows) ? A[(size_t)n * K + c] : 0.f;
    }
    __syncthreads();
    constexpr int G = BLOCK / M;
    constexpr int RPT = TM / G;
    const int j = tid % M;
    const int g = tid / M;
    float acc[RPT];
#pragma unroll
    for (int i = 0; i < RPT; i++) acc[i] = 0.f;
    for (int k = 0; k < K; k++) {
        float wk = W[(size_t)k * M + j];
#pragma unroll
        for (int i = 0; i < RPT; i++) acc[i] += As[g * RPT + i][k] * wk;
    }
    float bv = bias ? bias[j] : 0.f;
#pragma unroll
    for (int i = 0; i < RPT; i++) {
        int n = n0 + g * RPT + i;
        if (n < n_rows) {
            float v = acc[i] + bv;
            if (RELU) v = fmaxf(v, 0.f);
            C[(size_t)n * M + j] = v;
        }
    }
}

// ======================= CSR build =======================
__global__ void hist_kernel(const int* __restrict__ ei, int* __restrict__ deg) {
    int e = blockIdx.x * blockDim.x + threadIdx.x;
    if (e >= E2_EDGES) return;
    int d = (e < N_EDGES) ? ei[N_EDGES + e] : (e - N_EDGES);
    atomicAdd(deg + d, 1);
}

__global__ __launch_bounds__(256) void scan_block_kernel(const int* __restrict__ deg,
                                                         int* __restrict__ rowptr,
                                                         int* __restrict__ bsum) {
    __shared__ int sdata[256];
    const int b = blockIdx.x, t = threadIdx.x;
    const int base = b * 1024 + t * 4;
    int v[4]; int s = 0;
#pragma unroll
    for (int i = 0; i < 4; i++) {
        int idx = base + i;
        v[i] = (idx < N_NODES) ? deg[idx] : 0;
        s += v[i];
    }
    sdata[t] = s;
    __syncthreads();
    for (int o = 1; o < 256; o <<= 1) {
        int x = (t >= o) ? sdata[t - o] : 0;
        __syncthreads();
        sdata[t] += x;
        __syncthreads();
    }
    if (t == 255) bsum[b] = sdata[255];
    int run = sdata[t] - s;
#pragma unroll
    for (int i = 0; i < 4; i++) {
        int idx = base + i;
        if (idx < N_NODES) rowptr[idx] = run;
        run += v[i];
    }
}

__global__ void scan_bsum_kernel(int* __restrict__ bsum, int nb) {
    if (threadIdx.x == 0 && blockIdx.x == 0) {
        int run = 0;
        for (int i = 0; i < nb; i++) { int v = bsum[i]; bsum[i] = run; run += v; }
    }
}

__global__ void finalize_rowptr_kernel(int* __restrict__ rowptr, const int* __restrict__ bsum,
                                       int* __restrict__ cursor) {
    int i = blockIdx.x * blockDim.x + threadIdx.x;
    if (i >= N_NODES) return;
    int v = rowptr[i] + bsum[i >> 10];
    rowptr[i] = v;
    cursor[i] = v;
}

__global__ void scatter_kernel(const int* __restrict__ ei, int* __restrict__ cursor,
                               int* __restrict__ csr_src) {
    int e = blockIdx.x * blockDim.x + threadIdx.x;
    if (e >= E2_EDGES) return;
    int s, d;
    if (e < N_EDGES) { s = ei[e]; d = ei[N_EDGES + e]; }
    else             { s = d = e - N_EDGES; }
    int pos = atomicAdd(cursor + d, 1);
    csr_src[pos] = s;
}

// ===== agg v4: half-wave per edge, LDS-staged, single bf16 frag-major out ====
__global__ __launch_bounds__(256) void gat_agg_v3_kernel(
    const int* __restrict__ csr_src, const int* __restrict__ rowptr,
    const int* __restrict__ deg, const unsigned short* __restrict__ h,
    const float* __restrict__ als, const float* __restrict__ ald,
    const float* __restrict__ bias, unsigned short* __restrict__ outh) {
    constexpr int LP = 264;            // LDS row stride (shorts), 16B-aligned
    __shared__ unsigned short smh[16 * LP];
    const int wave = threadIdx.x >> 6, lane = threadIdx.x & 63;
    const int cl = lane & 31, half = lane >> 5;
    const int head = cl >> 3;          // 8 lanes per head (8 ch each)
    const int rt = blockIdx.x;         // row tile: nodes rt*16 .. rt*16+15
    float bv[8];
#pragma unroll
    for (int i = 0; i < 8; i++) bv[i] = bias[cl * 8 + i];

    for (int nn = 0; nn < 4; nn++) {
        const int node = rt * 16 + wave * 4 + nn;
        const int start = rowptr[node];
        const int len = deg[node];
        const float ad = ald[(node << 2) + head];
        float z = 0.f;
        float a[8];
#pragma unroll
        for (int i = 0; i < 8; i++) a[i] = 0.f;
        const unsigned short* hp = h + cl * 8;
        int k = 0;
        for (; k + 8 <= len; k += 8) {
            int s0 = csr_src[start + k + 0 + half];
            int s1 = csr_src[start + k + 2 + half];
            int s2 = csr_src[start + k + 4 + half];
            int s3 = csr_src[start + k + 6 + half];
            float x0 = als[(s0 << 2) + head] + ad;
            float x1 = als[(s1 << 2) + head] + ad;
            float x2 = als[(s2 << 2) + head] + ad;
            float x3 = als[(s3 << 2) + head] + ad;
            us8 h0 = *(const us8*)(hp + ((size_t)s0 << 8));
            us8 h1 = *(const us8*)(hp + ((size_t)s1 << 8));
            us8 h2 = *(const us8*)(hp + ((size_t)s2 << 8));
            us8 h3 = *(const us8*)(hp + ((size_t)s3 << 8));
            x0 = (x0 > 0.f) ? x0 : 0.2f * x0;
            x1 = (x1 > 0.f) ? x1 : 0.2f * x1;
            x2 = (x2 > 0.f) ? x2 : 0.2f * x2;
            x3 = (x3 > 0.f) ? x3 : 0.2f * x3;
            float p0 = __expf(x0), p1 = __expf(x1);
            float p2 = __expf(x2), p3 = __expf(x3);
            z += p0 + p1 + p2 + p3;
#pragma unroll
            for (int i = 0; i < 8; i++)
                a[i] += p0 * bf2f(h0[i]) + p1 * bf2f(h1[i])
                      + p2 * bf2f(h2[i]) + p3 * bf2f(h3[i]);
        }
        for (; k < len; k += 2) {
            int e = k + half;
            bool valid = (e < len);
            int s0 = csr_src[start + (valid ? e : 0)];
            float x0 = als[(s0 << 2) + head] + ad;
            x0 = (x0 > 0.f) ? x0 : 0.2f * x0;
            float p0 = valid ? __expf(x0) : 0.f;
            us8 h0 = *(const us8*)(hp + ((size_t)s0 << 8));
            z += p0;
#pragma unroll
            for (int i = 0; i < 8; i++) a[i] += p0 * bf2f(h0[i]);
        }
        z += __shfl_xor(z, 32);
#pragma unroll
        for (int i = 0; i < 8; i++) a[i] += __shfl_xor(a[i], 32);
        if (half == 0) {
            float inv = 1.f / (z + 1e-16f);
            us8 vh;
#pragma unroll
            for (int i = 0; i < 8; i++) {
                float v = fmaxf(a[i] * inv + bv[i], 0.f);   // relu (layers 1,2)
                vh[i] = f2bf(v);
            }
            int nl = wave * 4 + nn;     // node&15
            *(us8*)(smh + nl * LP + cl * 8) = vh;
        }
    }
    __syncthreads();
    // cooperative coalesced frag-major write: 8 chunks x 64 lanes x 16B
#pragma unroll
    for (int f = threadIdx.x; f < 512; f += 256) {
        int chunk = f >> 6, ln = f & 63;
        int quad = ln >> 4, l16 = ln & 15;
        us8 vh = *(const us8*)(smh + l16 * LP + chunk * 32 + quad * 8);
        size_t dst = (((size_t)rt * 8 + chunk) * 64 + ln) * 8;
        *(us8*)(outh + dst) = vh;
    }
}

// ===== layer-3 agg: H=1, C=64, no-max softmax, fp32 out =====
__global__ __launch_bounds__(256) void gat_agg_h1_kernel(
    const int* __restrict__ csr_src, const int* __restrict__ rowptr,
    const int* __restrict__ deg, const unsigned short* __restrict__ h,
    const float* __restrict__ als, const float* __restrict__ ald,
    const float* __restrict__ bias, float* __restrict__ out, int n) {
    const int lane = threadIdx.x & 63;
    const int node = (blockIdx.x << 2) + (threadIdx.x >> 6);
    if (node >= n) return;
    const int start = rowptr[node];
    const int len = deg[node];
    const float ad = ald[node];
    float z = 0.f, acc = 0.f;
    int k = 0;
    for (; k + 4 <= len; k += 4) {
        int s0 = csr_src[start + k + 0];
        int s1 = csr_src[start + k + 1];
        int s2 = csr_src[start + k + 2];
        int s3 = csr_src[start + k + 3];
        float a0 = als[s0], a1 = als[s1], a2 = als[s2], a3 = als[s3];
        float h0 = bf2f(h[((size_t)s0 << 6) + lane]);
        float h1 = bf2f(h[((size_t)s1 << 6) + lane]);
        float h2 = bf2f(h[((size_t)s2 << 6) + lane]);
        float h3 = bf2f(h[((size_t)s3 << 6) + lane]);
        float x0 = a0 + ad; x0 = (x0 > 0.f) ? x0 : 0.2f * x0;
        float x1 = a1 + ad; x1 = (x1 > 0.f) ? x1 : 0.2f * x1;
        float x2 = a2 + ad; x2 = (x2 > 0.f) ? x2 : 0.2f * x2;
        float x3 = a3 + ad; x3 = (x3 > 0.f) ? x3 : 0.2f * x3;
        float p0 = __expf(x0), p1 = __expf(x1);
        float p2 = __expf(x2), p3 = __expf(x3);
        z += p0 + p1 + p2 + p3;
        acc += p0 * h0 + p1 * h1 + p2 * h2 + p3 * h3;
    }
    for (; k < len; k++) {
        int s0 = csr_src[start + k];
        float x0 = als[s0] + ad; x0 = (x0 > 0.f) ? x0 : 0.2f * x0;
        float h0 = bf2f(h[((size_t)s0 << 6) + lane]);
        float p0 = __expf(x0);
        z += p0;
        acc += p0 * h0;
    }
    out[((size_t)node << 6) + lane] = acc / (z + 1e-16f) + bias[lane];
}

// ---------- mean pooling over (sorted) batch via binary search ----------
__global__ __launch_bounds__(64) void pool_kernel(const float* __restrict__ h3,
                                                  const int* __restrict__ batch,
                                                  float* __restrict__ xg) {
    const int b = blockIdx.x;
    const int j = threadIdx.x;
    int lo = 0, hi = N_NODES;
    while (lo < hi) { int mid = (lo + hi) >> 1; if (batch[mid] < b) lo = mid + 1; else hi = mid; }
    const int start = lo;
    hi = N_NODES;
    while (lo < hi) { int mid = (lo + hi) >> 1; if (batch[mid] < b + 1) lo = mid + 1; else hi = mid; }
    const int end = lo;
    float s = 0.f;
    for (int n = start; n < end; n++) s += h3[(size_t)n * CH + j];
    xg[b * CH + j] = s / fmaxf((float)(end - start), 1.f);
}

// ---------- MLP layer 2 + LayerNorm, one block per graph ----------
__global__ __launch_bounds__(256) void mlp2_ln_kernel(
    const float* __restrict__ y1, const float* __restrict__ Wm2,
    const float* __restrict__ bm2, const float* __restrict__ g2,
    const float* __restrict__ be2, float* __restrict__ out) {
    const int b = blockIdx.x;
    const int j = threadIdx.x;
    __shared__ float yr[NHID];
    yr[j] = y1[(size_t)b * NHID + j];
    __syncthreads();
    float acc = bm2[j];
#pragma unroll 8
    for (int k = 0; k < NHID; k++) acc += yr[k] * Wm2[(size_t)k * NOUT + j];
    float s = acc, s2 = acc * acc;
    for (int o = 32; o > 0; o >>= 1) {
        s += __shfl_down(s, o);
        s2 += __shfl_down(s2, o);
    }
    __shared__ float red[8];
    __shared__ float mv[2];
    int wave = j >> 6, lane = j & 63;
    if (lane == 0) { red[wave] = s; red[4 + wave] = s2; }
    __syncthreads();
    if (j == 0) {
        float ts = red[0] + red[1] + red[2] + red[3];
        float ts2 = red[4] + red[5] + red[6] + red[7];
        float mu = ts / (float)NOUT;
        float var = ts2 / (float)NOUT - mu * mu;
        mv[0] = mu;
        mv[1] = rsqrtf(var + 1e-5f);
    }
    __syncthreads();
    out[(size_t)b * NOUT + j] = (acc - mv[0]) * mv[1] * g2[j] + be2[j];
}

extern "C" void kernel_launch(void* const* d_in, const int* in_sizes, int n_in,
                              void* d_out, int out_size, void* d_ws, size_t ws_size,
                              hipStream_t stream) {
    const float* x      = (const float*)d_in[0];
    const int*   ei     = (const int*)d_in[1];
    const int*   batch  = (const int*)d_in[2];
    const float* W1     = (const float*)d_in[3];
    const float* as1    = (const float*)d_in[4];
    const float* ad1    = (const float*)d_in[5];
    const float* b1     = (const float*)d_in[6];
    const float* W2     = (const float*)d_in[7];
    const float* as2    = (const float*)d_in[8];
    const float* ad2    = (const float*)d_in[9];
    const float* b2     = (const float*)d_in[10];
    const float* W3     = (const float*)d_in[11];
    const float* as3    = (const float*)d_in[12];
    const float* ad3    = (const float*)d_in[13];
    const float* b3     = (const float*)d_in[14];
    const float* Wm1    = (const float*)d_in[15];
    const float* bm1    = (const float*)d_in[16];
    const float* Wm2    = (const float*)d_in[17];
    const float* bm2    = (const float*)d_in[18];
    const float* g2     = (const float*)d_in[19];
    const float* be2    = (const float*)d_in[20];
    float* out = (float*)d_out;

    // workspace layout
    unsigned short* bufH = (unsigned short*)d_ws;                  // N*HC bf16 (row-major h)
    unsigned short* aggh = bufH + (size_t)N_NODES * HC;            // N_PAD*HC frag-major (bf16)
    unsigned short* xh   = aggh + (size_t)N_PAD * HC;              // N_PAD*F_IN
    unsigned short* xl   = xh + (size_t)N_PAD * F_IN;              // N_PAD*F_IN
    float* bufO3 = (float*)(xl + (size_t)N_PAD * F_IN);            // N*CH fp32
    float* als   = bufO3 + (size_t)N_NODES * CH;                   // N*HEADS
    float* ald   = als + (size_t)N_NODES * HEADS;                  // N*HEADS
    float* xg    = ald + (size_t)N_NODES * HEADS;                  // NB*CH
    float* y1    = xg + (size_t)NB * CH;                           // NB*NHID
    int* deg     = (int*)(y1 + (size_t)NB * NHID);                 // N
    int* rowptr  = deg + N_NODES;                                  // N
    int* cursor  = rowptr + N_NODES;                               // N
    int* bsum    = cursor + N_NODES;                               // <=64
    int* csr_src = bsum + 64;                                      // E2
    unsigned short* wt1h = (unsigned short*)(csr_src + E2_EDGES);  // 256*32
    unsigned short* wt1l = wt1h + 256 * 32;
    unsigned short* wt2h = wt1l + 256 * 32;                        // 256*256
    unsigned short* wt2l = wt2h + 256 * 256;
    unsigned short* wt3h = wt2l + 256 * 256;                       // 64*256
    unsigned short* wt3l = wt3h + 64 * 256;

    const int BLK = 256;
    const int NSCAN = cdiv(N_NODES, 1024);

    // ===================== weight + input prep ==============================
    wconv_frag_kernel<<<cdiv(F_IN * HC, BLK), BLK, 0, stream>>>(W1, wt1h, wt1l, F_IN, HC);
    wconv_frag_kernel<<<cdiv(HC * HC, BLK), BLK, 0, stream>>>(W2, wt2h, wt2l, HC, HC);
    wconv_frag_kernel<<<cdiv(HC * CH, BLK), BLK, 0, stream>>>(W3, wt3h, wt3l, HC, CH);
    split_frag_kernel<<<cdiv(N_NODES * F_IN, BLK), BLK, 0, stream>>>(x, xh, xl, N_NODES);

    // ===================== CSR build (dst-sorted adjacency) ==================
    hipMemsetAsync(deg, 0, (size_t)N_NODES * sizeof(int), stream);
    hist_kernel<<<cdiv(E2_EDGES, BLK), BLK, 0, stream>>>(ei, deg);
    scan_block_kernel<<<NSCAN, 256, 0, stream>>>(deg, rowptr, bsum);
    scan_bsum_kernel<<<1, 64, 0, stream>>>(bsum, NSCAN);
    finalize_rowptr_kernel<<<cdiv(N_NODES, BLK), BLK, 0, stream>>>(rowptr, bsum, cursor);
    scatter_kernel<<<cdiv(E2_EDGES, BLK), BLK, 0, stream>>>(ei, cursor, csr_src);

    // ===================== Layer 1 (F_IN -> H*C) =====================
    mfma_lin_fused_kernel<F_IN, HC, true><<<cdiv(N_NODES, 64), 256, 0, stream>>>(
        xh, xl, wt1h, wt1l, as1, ad1, bufH, als, ald, N_NODES);
    gat_agg_v3_kernel<<<N_NODES / 16, 256, 0, stream>>>(
        csr_src, rowptr, deg, bufH, als, ald, b1, aggh);

    // ===================== Layer 2 (H*C -> H*C) =====================
    mfma_lin_fused_kernel<HC, HC, false><<<cdiv(N_NODES, 64), 256, 0, stream>>>(
        aggh, nullptr, wt2h, wt2l, as2, ad2, bufH, als, ald, N_NODES);
    gat_agg_v3_kernel<<<N_NODES / 16, 256, 0, stream>>>(
        csr_src, rowptr, deg, bufH, als, ald, b2, aggh);

    // ===================== Layer 3 (H*C -> C, heads=1) =====================
    mfma_lin_fused_kernel<HC, CH, false><<<cdiv(N_NODES, 256), 256, 0, stream>>>(
        aggh, nullptr, wt3h, wt3l, as3, ad3, bufH, als, ald, N_NODES);
    gat_agg_h1_kernel<<<cdiv(N_NODES, 4), 256, 0, stream>>>(
        csr_src, rowptr, deg, bufH, als, ald, b3, bufO3, N_NODES);

    // ===================== Mean pooling (batch is sorted) =====================
    pool_kernel<<<NB, 64, 0, stream>>>(bufO3, batch, xg);

    // ===================== MLP head + LayerNorm =====================
    lin_kernel<CH, NHID, 16, 256, true><<<cdiv(NB, 16), 256, 0, stream>>>(
        xg, Wm1, bm1, y1, NB);
    mlp2_ln_kernel<<<NB, 256, 0, stream>>>(y1, Wm2, bm2, g2, be2, out);
}

// Round 16
// 396.046 us; speedup vs baseline: 1.5399x; 1.0396x over previous
//
#include <hip/hip_runtime.h>
#include <hip/hip_bf16.h>

#define N_NODES 50000
#define N_PAD 50176        // padded to 3136 row-tiles of 16
#define N_EDGES 500000
#define E2_EDGES 550000    // with self loops appended
#define F_IN 32
#define HEADS 4
#define CH 64
#define HC 256             // HEADS*CH
#define NB 1000
#define NHID 256
#define NOUT 256

static inline int cdiv(long long a, long long b) { return (int)((a + b - 1) / b); }

typedef __bf16 bf16x8 __attribute__((ext_vector_type(8)));
typedef unsigned short us8 __attribute__((ext_vector_type(8)));
typedef unsigned short us4 __attribute__((ext_vector_type(4)));
typedef float f32x4 __attribute__((ext_vector_type(4)));
union BU { us8 u; bf16x8 b; };

// round-to-nearest-even fp32 -> bf16 (bit pattern)
__device__ inline unsigned short f2bf(float f) {
    unsigned u = __float_as_uint(f);
    return (unsigned short)((u + 0x7fffu + ((u >> 16) & 1u)) >> 16);
}
__device__ inline float bf2f(unsigned short h) {
    return __uint_as_float(((unsigned)h) << 16);
}

// ---------- device helpers for fused prep ----------
__device__ inline void wconv_one(const float* __restrict__ W,
                                 unsigned short* __restrict__ Wf_hi,
                                 unsigned short* __restrict__ Wf_lo,
                                 int K, int M, int idx) {
    int k = idx / M, m = idx % M;
    float v = W[idx];
    unsigned short hi = f2bf(v);
    unsigned short lo = f2bf(v - bf2f(hi));
    int tcol = m >> 4, l16 = m & 15;
    int ch = k >> 5, quad = (k >> 3) & 3, j = k & 7;
    int NCH = K >> 5;
    size_t dst = ((((size_t)tcol * NCH + ch) * 64) + quad * 16 + l16) * 8 + j;
    Wf_hi[dst] = hi;
    Wf_lo[dst] = lo;
}

// ---------- fused prep: deg zero + x split (A-frag) + 3x W conv ----------
#define PREP_T0 N_NODES
#define PREP_T1 (PREP_T0 + N_NODES * F_IN)
#define PREP_T2 (PREP_T1 + F_IN * HC)
#define PREP_T3 (PREP_T2 + HC * HC)
#define PREP_T4 (PREP_T3 + HC * CH)
__global__ void prep_kernel(const float* __restrict__ x,
                            unsigned short* __restrict__ xh,
                            unsigned short* __restrict__ xl,
                            const float* __restrict__ W1,
                            unsigned short* __restrict__ wt1h, unsigned short* __restrict__ wt1l,
                            const float* __restrict__ W2,
                            unsigned short* __restrict__ wt2h, unsigned short* __restrict__ wt2l,
                            const float* __restrict__ W3,
                            unsigned short* __restrict__ wt3h, unsigned short* __restrict__ wt3l,
                            int* __restrict__ deg) {
    int t = blockIdx.x * blockDim.x + threadIdx.x;
    if (t < PREP_T0) {
        deg[t] = 0;
    } else if (t < PREP_T1) {
        int i = t - PREP_T0;
        int node = i / F_IN, c = i % F_IN;
        float v = x[i];
        unsigned short hi = f2bf(v);
        size_t dst = (((size_t)(node >> 4)) * 64 + ((c >> 3) & 3) * 16 + (node & 15)) * 8 + (c & 7);
        xh[dst] = hi;
        xl[dst] = f2bf(v - bf2f(hi));
    } else if (t < PREP_T2) {
        wconv_one(W1, wt1h, wt1l, F_IN, HC, t - PREP_T1);
    } else if (t < PREP_T3) {
        wconv_one(W2, wt2h, wt2l, HC, HC, t - PREP_T2);
    } else if (t < PREP_T4) {
        wconv_one(W3, wt3h, wt3l, HC, CH, t - PREP_T3);
    }
}

// ====== fused split-bf16 MFMA GEMM + attention logits (row-major Hout) ======
// ALO: A has a lo plane (3-term split). For agg outputs A is plain bf16
// (2-term: ah*bh + ah*bl).
template<int K, int M, bool ALO>
__global__ __launch_bounds__(256) void mfma_lin_fused_kernel(
    const unsigned short* __restrict__ Ah, const unsigned short* __restrict__ Al,
    const unsigned short* __restrict__ Wf_hi, const unsigned short* __restrict__ Wf_lo,
    const float* __restrict__ a_src, const float* __restrict__ a_dst,
    unsigned short* __restrict__ Hout, float* __restrict__ als,
    float* __restrict__ ald, int n_rows) {
    constexpr int NCH = K / 32;
    constexpr int CW = M / 64;
    constexpr int RW = 4 / CW;
    constexpr int H_ = M / 64;
    const int wave = threadIdx.x >> 6, lane = threadIdx.x & 63;
    const int quad = lane >> 4, l16 = lane & 15;
    const int head = wave % CW;
    const int col0 = head * 64;
    const int row0 = blockIdx.x * (RW * 64) + (wave / CW) * 64;
    const int rt0 = row0 >> 4;

    f32x4 acc[4][4];
#pragma unroll
    for (int rs = 0; rs < 4; rs++)
#pragma unroll
        for (int t = 0; t < 4; t++) acc[rs][t] = (f32x4){0.f, 0.f, 0.f, 0.f};

    const unsigned short* aph[4];
    const unsigned short* apl[4];
#pragma unroll
    for (int rs = 0; rs < 4; rs++) {
        size_t off = (((size_t)(rt0 + rs) * NCH) * 64 + lane) * 8;
        aph[rs] = Ah + off;
        if (ALO) apl[rs] = Al + off;
    }
    const unsigned short* bh = Wf_hi + ((size_t)(col0 >> 4) * NCH * 64 + lane) * 8;
    const unsigned short* bl = Wf_lo + ((size_t)(col0 >> 4) * NCH * 64 + lane) * 8;

#pragma unroll
    for (int ch = 0; ch < NCH; ch++) {
        BU a_h[4], a_l[4], b_h[4], b_l[4];
#pragma unroll
        for (int rs = 0; rs < 4; rs++) {
            a_h[rs].u = *(const us8*)(aph[rs] + ch * 512);
            if (ALO) a_l[rs].u = *(const us8*)(apl[rs] + ch * 512);
        }
#pragma unroll
        for (int t = 0; t < 4; t++) {
            b_h[t].u = *(const us8*)(bh + (size_t)(t * NCH + ch) * 512);
            b_l[t].u = *(const us8*)(bl + (size_t)(t * NCH + ch) * 512);
        }
#pragma unroll
        for (int t = 0; t < 4; t++) {
#pragma unroll
            for (int rs = 0; rs < 4; rs++) {
                acc[rs][t] = __builtin_amdgcn_mfma_f32_16x16x32_bf16(a_h[rs].b, b_h[t].b, acc[rs][t], 0, 0, 0);
                acc[rs][t] = __builtin_amdgcn_mfma_f32_16x16x32_bf16(a_h[rs].b, b_l[t].b, acc[rs][t], 0, 0, 0);
                if (ALO)
                    acc[rs][t] = __builtin_amdgcn_mfma_f32_16x16x32_bf16(a_l[rs].b, b_h[t].b, acc[rs][t], 0, 0, 0);
            }
        }
    }

    float sv[4], dv[4];
#pragma unroll
    for (int t = 0; t < 4; t++) {
        sv[t] = a_src[col0 + t * 16 + l16];
        dv[t] = a_dst[col0 + t * 16 + l16];
    }
#pragma unroll
    for (int rs = 0; rs < 4; rs++) {
        const int orow0 = row0 + rs * 16 + quad * 4;
#pragma unroll
        for (int i = 0; i < 4; i++) {
            int r = orow0 + i;
            bool ok = (r < n_rows);
            float ps = 0.f, pd = 0.f;
#pragma unroll
            for (int t = 0; t < 4; t++) {
                float v = acc[rs][t][i];
                ps += v * sv[t];
                pd += v * dv[t];
                if (ok) Hout[(size_t)r * M + col0 + t * 16 + l16] = f2bf(v);
            }
            ps += __shfl_xor(ps, 1);  pd += __shfl_xor(pd, 1);
            ps += __shfl_xor(ps, 2);  pd += __shfl_xor(pd, 2);
            ps += __shfl_xor(ps, 4);  pd += __shfl_xor(pd, 4);
            ps += __shfl_xor(ps, 8);  pd += __shfl_xor(pd, 8);
            if (l16 == 0 && ok) {
                als[r * H_ + head] = ps;
                ald[r * H_ + head] = pd;
            }
        }
    }
}

// ---------- generic small GEMM (MLP layer 1) ----------
template<int K, int M, int TM, int BLOCK, bool RELU>
__global__ __launch_bounds__(BLOCK) void lin_kernel(
    const float* __restrict__ A, const float* __restrict__ W,
    const float* __restrict__ bias, float* __restrict__ C, int n_rows) {
    __shared__ float As[TM][K];
    const int n0 = blockIdx.x * TM;
    const int tid = threadIdx.x;
    for (int idx = tid; idx < TM * K; idx += BLOCK) {
        int r = idx / K, c = idx % K;
        int n = n0 + r;
        As[r][c] = (n < n_rows) ? A[(size_t)n * K + c] : 0.f;
    }
    __syncthreads();
    constexpr int G = BLOCK / M;
    constexpr int RPT = TM / G;
    const int j = tid % M;
    const int g = tid / M;
    float acc[RPT];
#pragma unroll
    for (int i = 0; i < RPT; i++) acc[i] = 0.f;
    for (int k = 0; k < K; k++) {
        float wk = W[(size_t)k * M + j];
#pragma unroll
        for (int i = 0; i < RPT; i++) acc[i] += As[g * RPT + i][k] * wk;
    }
    float bv = bias ? bias[j] : 0.f;
#pragma unroll
    for (int i = 0; i < RPT; i++) {
        int n = n0 + g * RPT + i;
        if (n < n_rows) {
            float v = acc[i] + bv;
            if (RELU) v = fmaxf(v, 0.f);
            C[(size_t)n * M + j] = v;
        }
    }
}

// ======================= CSR build =======================
__global__ void hist_kernel(const int* __restrict__ ei, int* __restrict__ deg) {
    int e = blockIdx.x * blockDim.x + threadIdx.x;
    if (e >= E2_EDGES) return;
    int d = (e < N_EDGES) ? ei[N_EDGES + e] : (e - N_EDGES);
    atomicAdd(deg + d, 1);
}

__global__ __launch_bounds__(256) void scan_block_kernel(const int* __restrict__ deg,
                                                         int* __restrict__ rowptr,
                                                         int* __restrict__ bsum) {
    __shared__ int sdata[256];
    const int b = blockIdx.x, t = threadIdx.x;
    const int base = b * 1024 + t * 4;
    int v[4]; int s = 0;
#pragma unroll
    for (int i = 0; i < 4; i++) {
        int idx = base + i;
        v[i] = (idx < N_NODES) ? deg[idx] : 0;
        s += v[i];
    }
    sdata[t] = s;
    __syncthreads();
    for (int o = 1; o < 256; o <<= 1) {
        int x = (t >= o) ? sdata[t - o] : 0;
        __syncthreads();
        sdata[t] += x;
        __syncthreads();
    }
    if (t == 255) bsum[b] = sdata[255];
    int run = sdata[t] - s;
#pragma unroll
    for (int i = 0; i < 4; i++) {
        int idx = base + i;
        if (idx < N_NODES) rowptr[idx] = run;
        run += v[i];
    }
}

__global__ void scan_bsum_kernel(int* __restrict__ bsum, int nb) {
    if (threadIdx.x == 0 && blockIdx.x == 0) {
        int run = 0;
        for (int i = 0; i < nb; i++) { int v = bsum[i]; bsum[i] = run; run += v; }
    }
}

__global__ void finalize_rowptr_kernel(int* __restrict__ rowptr, const int* __restrict__ bsum,
                                       int* __restrict__ cursor) {
    int i = blockIdx.x * blockDim.x + threadIdx.x;
    if (i >= N_NODES) return;
    int v = rowptr[i] + bsum[i >> 10];
    rowptr[i] = v;
    cursor[i] = v;
}

__global__ void scatter_kernel(const int* __restrict__ ei, int* __restrict__ cursor,
                               int* __restrict__ csr_src) {
    int e = blockIdx.x * blockDim.x + threadIdx.x;
    if (e >= E2_EDGES) return;
    int s, d;
    if (e < N_EDGES) { s = ei[e]; d = ei[N_EDGES + e]; }
    else             { s = d = e - N_EDGES; }
    int pos = atomicAdd(cursor + d, 1);
    csr_src[pos] = s;
}

// ===== agg v5: predicated 8-wide loop (clamped idx), half-wave per edge, =====
// LDS-staged, single bf16 frag-major out. avg deg=11 -> 2 iterations/node
// with 4 gathers in flight each (removes the serial 2-wide tail of v3).
__global__ __launch_bounds__(256) void gat_agg_v3_kernel(
    const int* __restrict__ csr_src, const int* __restrict__ rowptr,
    const int* __restrict__ deg, const unsigned short* __restrict__ h,
    const float* __restrict__ als, const float* __restrict__ ald,
    const float* __restrict__ bias, unsigned short* __restrict__ outh) {
    constexpr int LP = 264;            // LDS row stride (shorts), 16B-aligned
    __shared__ unsigned short smh[16 * LP];
    const int wave = threadIdx.x >> 6, lane = threadIdx.x & 63;
    const int cl = lane & 31, half = lane >> 5;
    const int head = cl >> 3;          // 8 lanes per head (8 ch each)
    const int rt = blockIdx.x;         // row tile: nodes rt*16 .. rt*16+15
    float bv[8];
#pragma unroll
    for (int i = 0; i < 8; i++) bv[i] = bias[cl * 8 + i];

    for (int nn = 0; nn < 4; nn++) {
        const int node = rt * 16 + wave * 4 + nn;
        const int start = rowptr[node];
        const int len = deg[node];
        const float ad = ald[(node << 2) + head];
        float z = 0.f;
        float a[8];
#pragma unroll
        for (int i = 0; i < 8; i++) a[i] = 0.f;
        const unsigned short* hp = h + cl * 8;
        for (int k = 0; k < len; k += 8) {
            int e0 = k + 0 + half, e1 = k + 2 + half;
            int e2 = k + 4 + half, e3 = k + 6 + half;
            int lm = len - 1;
            int s0 = csr_src[start + min(e0, lm)];
            int s1 = csr_src[start + min(e1, lm)];
            int s2 = csr_src[start + min(e2, lm)];
            int s3 = csr_src[start + min(e3, lm)];
            us8 h0 = *(const us8*)(hp + ((size_t)s0 << 8));
            us8 h1 = *(const us8*)(hp + ((size_t)s1 << 8));
            us8 h2 = *(const us8*)(hp + ((size_t)s2 << 8));
            us8 h3 = *(const us8*)(hp + ((size_t)s3 << 8));
            float x0 = als[(s0 << 2) + head] + ad;
            float x1 = als[(s1 << 2) + head] + ad;
            float x2 = als[(s2 << 2) + head] + ad;
            float x3 = als[(s3 << 2) + head] + ad;
            x0 = (x0 > 0.f) ? x0 : 0.2f * x0;
            x1 = (x1 > 0.f) ? x1 : 0.2f * x1;
            x2 = (x2 > 0.f) ? x2 : 0.2f * x2;
            x3 = (x3 > 0.f) ? x3 : 0.2f * x3;
            float p0 = (e0 < len) ? __expf(x0) : 0.f;
            float p1 = (e1 < len) ? __expf(x1) : 0.f;
            float p2 = (e2 < len) ? __expf(x2) : 0.f;
            float p3 = (e3 < len) ? __expf(x3) : 0.f;
            z += p0 + p1 + p2 + p3;
#pragma unroll
            for (int i = 0; i < 8; i++)
                a[i] += p0 * bf2f(h0[i]) + p1 * bf2f(h1[i])
                      + p2 * bf2f(h2[i]) + p3 * bf2f(h3[i]);
        }
        z += __shfl_xor(z, 32);
#pragma unroll
        for (int i = 0; i < 8; i++) a[i] += __shfl_xor(a[i], 32);
        if (half == 0) {
            float inv = 1.f / (z + 1e-16f);
            us8 vh;
#pragma unroll
            for (int i = 0; i < 8; i++) {
                float v = fmaxf(a[i] * inv + bv[i], 0.f);   // relu (layers 1,2)
                vh[i] = f2bf(v);
            }
            int nl = wave * 4 + nn;     // node&15
            *(us8*)(smh + nl * LP + cl * 8) = vh;
        }
    }
    __syncthreads();
    // cooperative coalesced frag-major write: 8 chunks x 64 lanes x 16B
#pragma unroll
    for (int f = threadIdx.x; f < 512; f += 256) {
        int chunk = f >> 6, ln = f & 63;
        int quad = ln >> 4, l16 = ln & 15;
        us8 vh = *(const us8*)(smh + l16 * LP + chunk * 32 + quad * 8);
        size_t dst = (((size_t)rt * 8 + chunk) * 64 + ln) * 8;
        *(us8*)(outh + dst) = vh;
    }
}

// ===== layer-3 agg: H=1, C=64, predicated 4-wide, fp32 out =====
__global__ __launch_bounds__(256) void gat_agg_h1_kernel(
    const int* __restrict__ csr_src, const int* __restrict__ rowptr,
    const int* __restrict__ deg, const unsigned short* __restrict__ h,
    const float* __restrict__ als, const float* __restrict__ ald,
    const float* __restrict__ bias, float* __restrict__ out, int n) {
    const int lane = threadIdx.x & 63;
    const int node = (blockIdx.x << 2) + (threadIdx.x >> 6);
    if (node >= n) return;
    const int start = rowptr[node];
    const int len = deg[node];
    const float ad = ald[node];
    float z = 0.f, acc = 0.f;
    for (int k = 0; k < len; k += 4) {
        int lm = len - 1;
        int s0 = csr_src[start + min(k + 0, lm)];
        int s1 = csr_src[start + min(k + 1, lm)];
        int s2 = csr_src[start + min(k + 2, lm)];
        int s3 = csr_src[start + min(k + 3, lm)];
        float h0 = bf2f(h[((size_t)s0 << 6) + lane]);
        float h1 = bf2f(h[((size_t)s1 << 6) + lane]);
        float h2 = bf2f(h[((size_t)s2 << 6) + lane]);
        float h3 = bf2f(h[((size_t)s3 << 6) + lane]);
        float x0 = als[s0] + ad; x0 = (x0 > 0.f) ? x0 : 0.2f * x0;
        float x1 = als[s1] + ad; x1 = (x1 > 0.f) ? x1 : 0.2f * x1;
        float x2 = als[s2] + ad; x2 = (x2 > 0.f) ? x2 : 0.2f * x2;
        float x3 = als[s3] + ad; x3 = (x3 > 0.f) ? x3 : 0.2f * x3;
        float p0 = __expf(x0);
        float p1 = (k + 1 < len) ? __expf(x1) : 0.f;
        float p2 = (k + 2 < len) ? __expf(x2) : 0.f;
        float p3 = (k + 3 < len) ? __expf(x3) : 0.f;
        z += p0 + p1 + p2 + p3;
        acc += p0 * h0 + p1 * h1 + p2 * h2 + p3 * h3;
    }
    out[((size_t)node << 6) + lane] = acc / (z + 1e-16f) + bias[lane];
}

// ---------- mean pooling over (sorted) batch via binary search ----------
__global__ __launch_bounds__(64) void pool_kernel(const float* __restrict__ h3,
                                                  const int* __restrict__ batch,
                                                  float* __restrict__ xg) {
    const int b = blockIdx.x;
    const int j = threadIdx.x;
    int lo = 0, hi = N_NODES;
    while (lo < hi) { int mid = (lo + hi) >> 1; if (batch[mid] < b) lo = mid + 1; else hi = mid; }
    const int start = lo;
    hi = N_NODES;
    while (lo < hi) { int mid = (lo + hi) >> 1; if (batch[mid] < b + 1) lo = mid + 1; else hi = mid; }
    const int end = lo;
    float s = 0.f;
    for (int n = start; n < end; n++) s += h3[(size_t)n * CH + j];
    xg[b * CH + j] = s / fmaxf((float)(end - start), 1.f);
}

// ---------- MLP layer 2 + LayerNorm, one block per graph ----------
__global__ __launch_bounds__(256) void mlp2_ln_kernel(
    const float* __restrict__ y1, const float* __restrict__ Wm2,
    const float* __restrict__ bm2, const float* __restrict__ g2,
    const float* __restrict__ be2, float* __restrict__ out) {
    const int b = blockIdx.x;
    const int j = threadIdx.x;
    __shared__ float yr[NHID];
    yr[j] = y1[(size_t)b * NHID + j];
    __syncthreads();
    float acc = bm2[j];
#pragma unroll 8
    for (int k = 0; k < NHID; k++) acc += yr[k] * Wm2[(size_t)k * NOUT + j];
    float s = acc, s2 = acc * acc;
    for (int o = 32; o > 0; o >>= 1) {
        s += __shfl_down(s, o);
        s2 += __shfl_down(s2, o);
    }
    __shared__ float red[8];
    __shared__ float mv[2];
    int wave = j >> 6, lane = j & 63;
    if (lane == 0) { red[wave] = s; red[4 + wave] = s2; }
    __syncthreads();
    if (j == 0) {
        float ts = red[0] + red[1] + red[2] + red[3];
        float ts2 = red[4] + red[5] + red[6] + red[7];
        float mu = ts / (float)NOUT;
        float var = ts2 / (float)NOUT - mu * mu;
        mv[0] = mu;
        mv[1] = rsqrtf(var + 1e-5f);
    }
    __syncthreads();
    out[(size_t)b * NOUT + j] = (acc - mv[0]) * mv[1] * g2[j] + be2[j];
}

extern "C" void kernel_launch(void* const* d_in, const int* in_sizes, int n_in,
                              void* d_out, int out_size, void* d_ws, size_t ws_size,
                              hipStream_t stream) {
    const float* x      = (const float*)d_in[0];
    const int*   ei     = (const int*)d_in[1];
    const int*   batch  = (const int*)d_in[2];
    const float* W1     = (const float*)d_in[3];
    const float* as1    = (const float*)d_in[4];
    const float* ad1    = (const float*)d_in[5];
    const float* b1     = (const float*)d_in[6];
    const float* W2     = (const float*)d_in[7];
    const float* as2    = (const float*)d_in[8];
    const float* ad2    = (const float*)d_in[9];
    const float* b2     = (const float*)d_in[10];
    const float* W3     = (const float*)d_in[11];
    const float* as3    = (const float*)d_in[12];
    const float* ad3    = (const float*)d_in[13];
    const float* b3     = (const float*)d_in[14];
    const float* Wm1    = (const float*)d_in[15];
    const float* bm1    = (const float*)d_in[16];
    const float* Wm2    = (const float*)d_in[17];
    const float* bm2    = (const float*)d_in[18];
    const float* g2     = (const float*)d_in[19];
    const float* be2    = (const float*)d_in[20];
    float* out = (float*)d_out;

    // workspace layout
    unsigned short* bufH = (unsigned short*)d_ws;                  // N*HC bf16 (row-major h)
    unsigned short* aggh = bufH + (size_t)N_NODES * HC;            // N_PAD*HC frag-major (bf16)
    unsigned short* xh   = aggh + (size_t)N_PAD * HC;              // N_PAD*F_IN
    unsigned short* xl   = xh + (size_t)N_PAD * F_IN;              // N_PAD*F_IN
    float* bufO3 = (float*)(xl + (size_t)N_PAD * F_IN);            // N*CH fp32
    float* als   = bufO3 + (size_t)N_NODES * CH;                   // N*HEADS
    float* ald   = als + (size_t)N_NODES * HEADS;                  // N*HEADS
    float* xg    = ald + (size_t)N_NODES * HEADS;                  // NB*CH
    float* y1    = xg + (size_t)NB * CH;                           // NB*NHID
    int* deg     = (int*)(y1 + (size_t)NB * NHID);                 // N
    int* rowptr  = deg + N_NODES;                                  // N
    int* cursor  = rowptr + N_NODES;                               // N
    int* bsum    = cursor + N_NODES;                               // <=64
    int* csr_src = bsum + 64;                                      // E2
    unsigned short* wt1h = (unsigned short*)(csr_src + E2_EDGES);  // 256*32
    unsigned short* wt1l = wt1h + 256 * 32;
    unsigned short* wt2h = wt1l + 256 * 32;                        // 256*256
    unsigned short* wt2l = wt2h + 256 * 256;
    unsigned short* wt3h = wt2l + 256 * 256;                       // 64*256
    unsigned short* wt3l = wt3h + 64 * 256;

    const int BLK = 256;
    const int NSCAN = cdiv(N_NODES, 1024);

    // ===================== fused prep (deg=0, x split, 3x W conv) ===========
    prep_kernel<<<cdiv(PREP_T4, BLK), BLK, 0, stream>>>(
        x, xh, xl, W1, wt1h, wt1l, W2, wt2h, wt2l, W3, wt3h, wt3l, deg);

    // ===================== CSR build (dst-sorted adjacency) ==================
    hist_kernel<<<cdiv(E2_EDGES, BLK), BLK, 0, stream>>>(ei, deg);
    scan_block_kernel<<<NSCAN, 256, 0, stream>>>(deg, rowptr, bsum);
    scan_bsum_kernel<<<1, 64, 0, stream>>>(bsum, NSCAN);
    finalize_rowptr_kernel<<<cdiv(N_NODES, BLK), BLK, 0, stream>>>(rowptr, bsum, cursor);
    scatter_kernel<<<cdiv(E2_EDGES, BLK), BLK, 0, stream>>>(ei, cursor, csr_src);

    // ===================== Layer 1 (F_IN -> H*C) =====================
    mfma_lin_fused_kernel<F_IN, HC, true><<<cdiv(N_NODES, 64), 256, 0, stream>>>(
        xh, xl, wt1h, wt1l, as1, ad1, bufH, als, ald, N_NODES);
    gat_agg_v3_kernel<<<N_NODES / 16, 256, 0, stream>>>(
        csr_src, rowptr, deg, bufH, als, ald, b1, aggh);

    // ===================== Layer 2 (H*C -> H*C) =====================
    mfma_lin_fused_kernel<HC, HC, false><<<cdiv(N_NODES, 64), 256, 0, stream>>>(
        aggh, nullptr, wt2h, wt2l, as2, ad2, bufH, als, ald, N_NODES);
    gat_agg_v3_kernel<<<N_NODES / 16, 256, 0, stream>>>(
        csr_src, rowptr, deg, bufH, als, ald, b2, aggh);

    // ===================== Layer 3 (H*C -> C, heads=1) =====================
    mfma_lin_fused_kernel<HC, CH, false><<<cdiv(N_NODES, 256), 256, 0, stream>>>(
        aggh, nullptr, wt3h, wt3l, as3, ad3, bufH, als, ald, N_NODES);
    gat_agg_h1_kernel<<<cdiv(N_NODES, 4), 256, 0, stream>>>(
        csr_src, rowptr, deg, bufH, als, ald, b3, bufO3, N_NODES);

    // ===================== Mean pooling (batch is sorted) =====================
    pool_kernel<<<NB, 64, 0, stream>>>(bufO3, batch, xg);

    // ===================== MLP head + LayerNorm =====================
    lin_kernel<CH, NHID, 16, 256, true><<<cdiv(NB, 16), 256, 0, stream>>>(
        xg, Wm1, bm1, y1, NB);
    mlp2_ln_kernel<<<NB, 256, 0, stream>>>(y1, Wm2, bm2, g2, be2, out);
}

// Round 17
// 389.178 us; speedup vs baseline: 1.5670x; 1.0176x over previous
//
#include <hip/hip_runtime.h>
#include <hip/hip_bf16.h>

#define N_NODES 50000
#define N_PAD 50176        // padded to 3136 row-tiles of 16
#define N_EDGES 500000
#define E2_EDGES 550000    // with self loops appended
#define F_IN 32
#define HEADS 4
#define CH 64
#define HC 256             // HEADS*CH
#define NB 1000
#define NHID 256
#define NOUT 256

static inline int cdiv(long long a, long long b) { return (int)((a + b - 1) / b); }

typedef __bf16 bf16x8 __attribute__((ext_vector_type(8)));
typedef unsigned short us8 __attribute__((ext_vector_type(8)));
typedef unsigned short us4 __attribute__((ext_vector_type(4)));
typedef float f32x4 __attribute__((ext_vector_type(4)));
union BU { us8 u; bf16x8 b; };

// round-to-nearest-even fp32 -> bf16 (bit pattern)
__device__ inline unsigned short f2bf(float f) {
    unsigned u = __float_as_uint(f);
    return (unsigned short)((u + 0x7fffu + ((u >> 16) & 1u)) >> 16);
}
__device__ inline float bf2f(unsigned short h) {
    return __uint_as_float(((unsigned)h) << 16);
}

// ---------- device helpers for fused prep ----------
__device__ inline void wconv_one(const float* __restrict__ W,
                                 unsigned short* __restrict__ Wf_hi,
                                 unsigned short* __restrict__ Wf_lo,
                                 int K, int M, int idx) {
    int k = idx / M, m = idx % M;
    float v = W[idx];
    unsigned short hi = f2bf(v);
    unsigned short lo = f2bf(v - bf2f(hi));
    int tcol = m >> 4, l16 = m & 15;
    int ch = k >> 5, quad = (k >> 3) & 3, j = k & 7;
    int NCH = K >> 5;
    size_t dst = ((((size_t)tcol * NCH + ch) * 64) + quad * 16 + l16) * 8 + j;
    Wf_hi[dst] = hi;
    Wf_lo[dst] = lo;
}

// ---------- fused prep: deg zero + x split (A-frag) + 3x W conv ----------
#define PREP_T0 N_NODES
#define PREP_T1 (PREP_T0 + N_NODES * F_IN)
#define PREP_T2 (PREP_T1 + F_IN * HC)
#define PREP_T3 (PREP_T2 + HC * HC)
#define PREP_T4 (PREP_T3 + HC * CH)
__global__ void prep_kernel(const float* __restrict__ x,
                            unsigned short* __restrict__ xh,
                            unsigned short* __restrict__ xl,
                            const float* __restrict__ W1,
                            unsigned short* __restrict__ wt1h, unsigned short* __restrict__ wt1l,
                            const float* __restrict__ W2,
                            unsigned short* __restrict__ wt2h, unsigned short* __restrict__ wt2l,
                            const float* __restrict__ W3,
                            unsigned short* __restrict__ wt3h, unsigned short* __restrict__ wt3l,
                            int* __restrict__ deg) {
    int t = blockIdx.x * blockDim.x + threadIdx.x;
    if (t < PREP_T0) {
        deg[t] = 0;
    } else if (t < PREP_T1) {
        int i = t - PREP_T0;
        int node = i / F_IN, c = i % F_IN;
        float v = x[i];
        unsigned short hi = f2bf(v);
        size_t dst = (((size_t)(node >> 4)) * 64 + ((c >> 3) & 3) * 16 + (node & 15)) * 8 + (c & 7);
        xh[dst] = hi;
        xl[dst] = f2bf(v - bf2f(hi));
    } else if (t < PREP_T2) {
        wconv_one(W1, wt1h, wt1l, F_IN, HC, t - PREP_T1);
    } else if (t < PREP_T3) {
        wconv_one(W2, wt2h, wt2l, HC, HC, t - PREP_T2);
    } else if (t < PREP_T4) {
        wconv_one(W3, wt3h, wt3l, HC, CH, t - PREP_T3);
    }
}

// ====== fused split-bf16 MFMA GEMM + attention logits (row-major Hout) ======
template<int K, int M, bool ALO>
__global__ __launch_bounds__(256) void mfma_lin_fused_kernel(
    const unsigned short* __restrict__ Ah, const unsigned short* __restrict__ Al,
    const unsigned short* __restrict__ Wf_hi, const unsigned short* __restrict__ Wf_lo,
    const float* __restrict__ a_src, const float* __restrict__ a_dst,
    unsigned short* __restrict__ Hout, float* __restrict__ als,
    float* __restrict__ ald, int n_rows) {
    constexpr int NCH = K / 32;
    constexpr int CW = M / 64;
    constexpr int RW = 4 / CW;
    constexpr int H_ = M / 64;
    const int wave = threadIdx.x >> 6, lane = threadIdx.x & 63;
    const int quad = lane >> 4, l16 = lane & 15;
    const int head = wave % CW;
    const int col0 = head * 64;
    const int row0 = blockIdx.x * (RW * 64) + (wave / CW) * 64;
    const int rt0 = row0 >> 4;

    f32x4 acc[4][4];
#pragma unroll
    for (int rs = 0; rs < 4; rs++)
#pragma unroll
        for (int t = 0; t < 4; t++) acc[rs][t] = (f32x4){0.f, 0.f, 0.f, 0.f};

    const unsigned short* aph[4];
    const unsigned short* apl[4];
#pragma unroll
    for (int rs = 0; rs < 4; rs++) {
        size_t off = (((size_t)(rt0 + rs) * NCH) * 64 + lane) * 8;
        aph[rs] = Ah + off;
        if (ALO) apl[rs] = Al + off;
    }
    const unsigned short* bh = Wf_hi + ((size_t)(col0 >> 4) * NCH * 64 + lane) * 8;
    const unsigned short* bl = Wf_lo + ((size_t)(col0 >> 4) * NCH * 64 + lane) * 8;

#pragma unroll
    for (int ch = 0; ch < NCH; ch++) {
        BU a_h[4], a_l[4], b_h[4], b_l[4];
#pragma unroll
        for (int rs = 0; rs < 4; rs++) {
            a_h[rs].u = *(const us8*)(aph[rs] + ch * 512);
            if (ALO) a_l[rs].u = *(const us8*)(apl[rs] + ch * 512);
        }
#pragma unroll
        for (int t = 0; t < 4; t++) {
            b_h[t].u = *(const us8*)(bh + (size_t)(t * NCH + ch) * 512);
            b_l[t].u = *(const us8*)(bl + (size_t)(t * NCH + ch) * 512);
        }
#pragma unroll
        for (int t = 0; t < 4; t++) {
#pragma unroll
            for (int rs = 0; rs < 4; rs++) {
                acc[rs][t] = __builtin_amdgcn_mfma_f32_16x16x32_bf16(a_h[rs].b, b_h[t].b, acc[rs][t], 0, 0, 0);
                acc[rs][t] = __builtin_amdgcn_mfma_f32_16x16x32_bf16(a_h[rs].b, b_l[t].b, acc[rs][t], 0, 0, 0);
                if (ALO)
                    acc[rs][t] = __builtin_amdgcn_mfma_f32_16x16x32_bf16(a_l[rs].b, b_h[t].b, acc[rs][t], 0, 0, 0);
            }
        }
    }

    float sv[4], dv[4];
#pragma unroll
    for (int t = 0; t < 4; t++) {
        sv[t] = a_src[col0 + t * 16 + l16];
        dv[t] = a_dst[col0 + t * 16 + l16];
    }
#pragma unroll
    for (int rs = 0; rs < 4; rs++) {
        const int orow0 = row0 + rs * 16 + quad * 4;
#pragma unroll
        for (int i = 0; i < 4; i++) {
            int r = orow0 + i;
            bool ok = (r < n_rows);
            float ps = 0.f, pd = 0.f;
#pragma unroll
            for (int t = 0; t < 4; t++) {
                float v = acc[rs][t][i];
                ps += v * sv[t];
                pd += v * dv[t];
                if (ok) Hout[(size_t)r * M + col0 + t * 16 + l16] = f2bf(v);
            }
            ps += __shfl_xor(ps, 1);  pd += __shfl_xor(pd, 1);
            ps += __shfl_xor(ps, 2);  pd += __shfl_xor(pd, 2);
            ps += __shfl_xor(ps, 4);  pd += __shfl_xor(pd, 4);
            ps += __shfl_xor(ps, 8);  pd += __shfl_xor(pd, 8);
            if (l16 == 0 && ok) {
                als[r * H_ + head] = ps;
                ald[r * H_ + head] = pd;
            }
        }
    }
}

// ---------- generic small GEMM (MLP layer 1) ----------
template<int K, int M, int TM, int BLOCK, bool RELU>
__global__ __launch_bounds__(BLOCK) void lin_kernel(
    const float* __restrict__ A, const float* __restrict__ W,
    const float* __restrict__ bias, float* __restrict__ C, int n_rows) {
    __shared__ float As[TM][K];
    const int n0 = blockIdx.x * TM;
    const int tid = threadIdx.x;
    for (int idx = tid; idx < TM * K; idx += BLOCK) {
        int r = idx / K, c = idx % K;
        int n = n0 + r;
        As[r][c] = (n < n_rows) ? A[(size_t)n * K + c] : 0.f;
    }
    __syncthreads();
    constexpr int G = BLOCK / M;
    constexpr int RPT = TM / G;
    const int j = tid % M;
    const int g = tid / M;
    float acc[RPT];
#pragma unroll
    for (int i = 0; i < RPT; i++) acc[i] = 0.f;
    for (int k = 0; k < K; k++) {
        float wk = W[(size_t)k * M + j];
#pragma unroll
        for (int i = 0; i < RPT; i++) acc[i] += As[g * RPT + i][k] * wk;
    }
    float bv = bias ? bias[j] : 0.f;
#pragma unroll
    for (int i = 0; i < RPT; i++) {
        int n = n0 + g * RPT + i;
        if (n < n_rows) {
            float v = acc[i] + bv;
            if (RELU) v = fmaxf(v, 0.f);
            C[(size_t)n * M + j] = v;
        }
    }
}

// ======================= CSR build =======================
__global__ void hist_kernel(const int* __restrict__ ei, int* __restrict__ deg) {
    int e = blockIdx.x * blockDim.x + threadIdx.x;
    if (e >= E2_EDGES) return;
    int d = (e < N_EDGES) ? ei[N_EDGES + e] : (e - N_EDGES);
    atomicAdd(deg + d, 1);
}

__global__ __launch_bounds__(256) void scan_block_kernel(const int* __restrict__ deg,
                                                         int* __restrict__ rowptr,
                                                         int* __restrict__ bsum) {
    __shared__ int sdata[256];
    const int b = blockIdx.x, t = threadIdx.x;
    const int base = b * 1024 + t * 4;
    int v[4]; int s = 0;
#pragma unroll
    for (int i = 0; i < 4; i++) {
        int idx = base + i;
        v[i] = (idx < N_NODES) ? deg[idx] : 0;
        s += v[i];
    }
    sdata[t] = s;
    __syncthreads();
    for (int o = 1; o < 256; o <<= 1) {
        int x = (t >= o) ? sdata[t - o] : 0;
        __syncthreads();
        sdata[t] += x;
        __syncthreads();
    }
    if (t == 255) bsum[b] = sdata[255];
    int run = sdata[t] - s;
#pragma unroll
    for (int i = 0; i < 4; i++) {
        int idx = base + i;
        if (idx < N_NODES) rowptr[idx] = run;
        run += v[i];
    }
}

__global__ void scan_bsum_kernel(int* __restrict__ bsum, int nb) {
    if (threadIdx.x == 0 && blockIdx.x == 0) {
        int run = 0;
        for (int i = 0; i < nb; i++) { int v = bsum[i]; bsum[i] = run; run += v; }
    }
}

__global__ void finalize_rowptr_kernel(int* __restrict__ rowptr, const int* __restrict__ bsum,
                                       int* __restrict__ cursor) {
    int i = blockIdx.x * blockDim.x + threadIdx.x;
    if (i >= N_NODES) return;
    int v = rowptr[i] + bsum[i >> 10];
    rowptr[i] = v;
    cursor[i] = v;
}

__global__ void scatter_kernel(const int* __restrict__ ei, int* __restrict__ cursor,
                               int* __restrict__ csr_src) {
    int e = blockIdx.x * blockDim.x + threadIdx.x;
    if (e >= E2_EDGES) return;
    int s, d;
    if (e < N_EDGES) { s = ei[e]; d = ei[N_EDGES + e]; }
    else             { s = d = e - N_EDGES; }
    int pos = atomicAdd(cursor + d, 1);
    csr_src[pos] = s;
}

// ===== agg v5: predicated 8-wide loop (clamped idx), half-wave per edge, =====
// LDS-staged, single bf16 frag-major out.
__global__ __launch_bounds__(256) void gat_agg_v3_kernel(
    const int* __restrict__ csr_src, const int* __restrict__ rowptr,
    const int* __restrict__ deg, const unsigned short* __restrict__ h,
    const float* __restrict__ als, const float* __restrict__ ald,
    const float* __restrict__ bias, unsigned short* __restrict__ outh) {
    constexpr int LP = 264;            // LDS row stride (shorts), 16B-aligned
    __shared__ unsigned short smh[16 * LP];
    const int wave = threadIdx.x >> 6, lane = threadIdx.x & 63;
    const int cl = lane & 31, half = lane >> 5;
    const int head = cl >> 3;          // 8 lanes per head (8 ch each)
    const int rt = blockIdx.x;         // row tile: nodes rt*16 .. rt*16+15
    float bv[8];
#pragma unroll
    for (int i = 0; i < 8; i++) bv[i] = bias[cl * 8 + i];

    for (int nn = 0; nn < 4; nn++) {
        const int node = rt * 16 + wave * 4 + nn;
        const int start = rowptr[node];
        const int len = deg[node];
        const float ad = ald[(node << 2) + head];
        float z = 0.f;
        float a[8];
#pragma unroll
        for (int i = 0; i < 8; i++) a[i] = 0.f;
        const unsigned short* hp = h + cl * 8;
        for (int k = 0; k < len; k += 8) {
            int e0 = k + 0 + half, e1 = k + 2 + half;
            int e2 = k + 4 + half, e3 = k + 6 + half;
            int lm = len - 1;
            int s0 = csr_src[start + min(e0, lm)];
            int s1 = csr_src[start + min(e1, lm)];
            int s2 = csr_src[start + min(e2, lm)];
            int s3 = csr_src[start + min(e3, lm)];
            us8 h0 = *(const us8*)(hp + ((size_t)s0 << 8));
            us8 h1 = *(const us8*)(hp + ((size_t)s1 << 8));
            us8 h2 = *(const us8*)(hp + ((size_t)s2 << 8));
            us8 h3 = *(const us8*)(hp + ((size_t)s3 << 8));
            float x0 = als[(s0 << 2) + head] + ad;
            float x1 = als[(s1 << 2) + head] + ad;
            float x2 = als[(s2 << 2) + head] + ad;
            float x3 = als[(s3 << 2) + head] + ad;
            x0 = (x0 > 0.f) ? x0 : 0.2f * x0;
            x1 = (x1 > 0.f) ? x1 : 0.2f * x1;
            x2 = (x2 > 0.f) ? x2 : 0.2f * x2;
            x3 = (x3 > 0.f) ? x3 : 0.2f * x3;
            float p0 = (e0 < len) ? __expf(x0) : 0.f;
            float p1 = (e1 < len) ? __expf(x1) : 0.f;
            float p2 = (e2 < len) ? __expf(x2) : 0.f;
            float p3 = (e3 < len) ? __expf(x3) : 0.f;
            z += p0 + p1 + p2 + p3;
#pragma unroll
            for (int i = 0; i < 8; i++)
                a[i] += p0 * bf2f(h0[i]) + p1 * bf2f(h1[i])
                      + p2 * bf2f(h2[i]) + p3 * bf2f(h3[i]);
        }
        z += __shfl_xor(z, 32);
#pragma unroll
        for (int i = 0; i < 8; i++) a[i] += __shfl_xor(a[i], 32);
        if (half == 0) {
            float inv = 1.f / (z + 1e-16f);
            us8 vh;
#pragma unroll
            for (int i = 0; i < 8; i++) {
                float v = fmaxf(a[i] * inv + bv[i], 0.f);   // relu (layers 1,2)
                vh[i] = f2bf(v);
            }
            int nl = wave * 4 + nn;     // node&15
            *(us8*)(smh + nl * LP + cl * 8) = vh;
        }
    }
    __syncthreads();
    // cooperative coalesced frag-major write: 8 chunks x 64 lanes x 16B
#pragma unroll
    for (int f = threadIdx.x; f < 512; f += 256) {
        int chunk = f >> 6, ln = f & 63;
        int quad = ln >> 4, l16 = ln & 15;
        us8 vh = *(const us8*)(smh + l16 * LP + chunk * 32 + quad * 8);
        size_t dst = (((size_t)rt * 8 + chunk) * 64 + ln) * 8;
        *(us8*)(outh + dst) = vh;
    }
}

// ===== layer-3 agg v2: one wave/node, 8 edge-slots x 8 lanes (us8 = full ====
// 64-ch row per slot, 16B/lane), predicated clamp, shfl_xor slot-reduce.
// Replaces the 2B/lane scalar-gather version (12x fewer load instrs).
__global__ __launch_bounds__(256) void gat_agg_h1_kernel(
    const int* __restrict__ csr_src, const int* __restrict__ rowptr,
    const int* __restrict__ deg, const unsigned short* __restrict__ h,
    const float* __restrict__ als, const float* __restrict__ ald,
    const float* __restrict__ bias, float* __restrict__ out, int n) {
    const int wave = threadIdx.x >> 6, lane = threadIdx.x & 63;
    const int eg = lane >> 3, cg = lane & 7;   // edge slot, channel group
    const int node = (blockIdx.x << 2) + wave;
    if (node >= n) return;
    const int start = rowptr[node];
    const int len = deg[node];
    const float ad = ald[node];
    float z = 0.f;
    float a[8];
#pragma unroll
    for (int i = 0; i < 8; i++) a[i] = 0.f;
    const unsigned short* hp = h + cg * 8;
    for (int k = 0; k < len; k += 8) {
        int e = k + eg;
        int s0 = csr_src[start + min(e, len - 1)];
        us8 hv = *(const us8*)(hp + ((size_t)s0 << 6));
        float x = als[s0] + ad;
        x = (x > 0.f) ? x : 0.2f * x;
        float p = (e < len) ? __expf(x) : 0.f;
        z += p;
#pragma unroll
        for (int i = 0; i < 8; i++) a[i] += p * bf2f(hv[i]);
    }
    // reduce over the 8 edge slots (offsets 8,16,32)
#pragma unroll
    for (int off = 8; off <= 32; off <<= 1) {
        z += __shfl_xor(z, off);
#pragma unroll
        for (int i = 0; i < 8; i++) a[i] += __shfl_xor(a[i], off);
    }
    if (eg == 0) {
        float inv = 1.f / (z + 1e-16f);
        float* op = out + ((size_t)node << 6) + cg * 8;
        float4 o0, o1;
        o0.x = a[0] * inv + bias[cg * 8 + 0];
        o0.y = a[1] * inv + bias[cg * 8 + 1];
        o0.z = a[2] * inv + bias[cg * 8 + 2];
        o0.w = a[3] * inv + bias[cg * 8 + 3];
        o1.x = a[4] * inv + bias[cg * 8 + 4];
        o1.y = a[5] * inv + bias[cg * 8 + 5];
        o1.z = a[6] * inv + bias[cg * 8 + 6];
        o1.w = a[7] * inv + bias[cg * 8 + 7];
        *(float4*)op = o0;
        *(float4*)(op + 4) = o1;
    }
}

// ---------- mean pooling over (sorted) batch via binary search ----------
__global__ __launch_bounds__(64) void pool_kernel(const float* __restrict__ h3,
                                                  const int* __restrict__ batch,
                                                  float* __restrict__ xg) {
    const int b = blockIdx.x;
    const int j = threadIdx.x;
    int lo = 0, hi = N_NODES;
    while (lo < hi) { int mid = (lo + hi) >> 1; if (batch[mid] < b) lo = mid + 1; else hi = mid; }
    const int start = lo;
    hi = N_NODES;
    while (lo < hi) { int mid = (lo + hi) >> 1; if (batch[mid] < b + 1) lo = mid + 1; else hi = mid; }
    const int end = lo;
    float s = 0.f;
    for (int n = start; n < end; n++) s += h3[(size_t)n * CH + j];
    xg[b * CH + j] = s / fmaxf((float)(end - start), 1.f);
}

// ---------- MLP layer 2 + LayerNorm, one block per graph ----------
__global__ __launch_bounds__(256) void mlp2_ln_kernel(
    const float* __restrict__ y1, const float* __restrict__ Wm2,
    const float* __restrict__ bm2, const float* __restrict__ g2,
    const float* __restrict__ be2, float* __restrict__ out) {
    const int b = blockIdx.x;
    const int j = threadIdx.x;
    __shared__ float yr[NHID];
    yr[j] = y1[(size_t)b * NHID + j];
    __syncthreads();
    float acc = bm2[j];
#pragma unroll 8
    for (int k = 0; k < NHID; k++) acc += yr[k] * Wm2[(size_t)k * NOUT + j];
    float s = acc, s2 = acc * acc;
    for (int o = 32; o > 0; o >>= 1) {
        s += __shfl_down(s, o);
        s2 += __shfl_down(s2, o);
    }
    __shared__ float red[8];
    __shared__ float mv[2];
    int wave = j >> 6, lane = j & 63;
    if (lane == 0) { red[wave] = s; red[4 + wave] = s2; }
    __syncthreads();
    if (j == 0) {
        float ts = red[0] + red[1] + red[2] + red[3];
        float ts2 = red[4] + red[5] + red[6] + red[7];
        float mu = ts / (float)NOUT;
        float var = ts2 / (float)NOUT - mu * mu;
        mv[0] = mu;
        mv[1] = rsqrtf(var + 1e-5f);
    }
    __syncthreads();
    out[(size_t)b * NOUT + j] = (acc - mv[0]) * mv[1] * g2[j] + be2[j];
}

extern "C" void kernel_launch(void* const* d_in, const int* in_sizes, int n_in,
                              void* d_out, int out_size, void* d_ws, size_t ws_size,
                              hipStream_t stream) {
    const float* x      = (const float*)d_in[0];
    const int*   ei     = (const int*)d_in[1];
    const int*   batch  = (const int*)d_in[2];
    const float* W1     = (const float*)d_in[3];
    const float* as1    = (const float*)d_in[4];
    const float* ad1    = (const float*)d_in[5];
    const float* b1     = (const float*)d_in[6];
    const float* W2     = (const float*)d_in[7];
    const float* as2    = (const float*)d_in[8];
    const float* ad2    = (const float*)d_in[9];
    const float* b2     = (const float*)d_in[10];
    const float* W3     = (const float*)d_in[11];
    const float* as3    = (const float*)d_in[12];
    const float* ad3    = (const float*)d_in[13];
    const float* b3     = (const float*)d_in[14];
    const float* Wm1    = (const float*)d_in[15];
    const float* bm1    = (const float*)d_in[16];
    const float* Wm2    = (const float*)d_in[17];
    const float* bm2    = (const float*)d_in[18];
    const float* g2     = (const float*)d_in[19];
    const float* be2    = (const float*)d_in[20];
    float* out = (float*)d_out;

    // workspace layout
    unsigned short* bufH = (unsigned short*)d_ws;                  // N*HC bf16 (row-major h)
    unsigned short* aggh = bufH + (size_t)N_NODES * HC;            // N_PAD*HC frag-major (bf16)
    unsigned short* xh   = aggh + (size_t)N_PAD * HC;              // N_PAD*F_IN
    unsigned short* xl   = xh + (size_t)N_PAD * F_IN;              // N_PAD*F_IN
    float* bufO3 = (float*)(xl + (size_t)N_PAD * F_IN);            // N*CH fp32
    float* als   = bufO3 + (size_t)N_NODES * CH;                   // N*HEADS
    float* ald   = als + (size_t)N_NODES * HEADS;                  // N*HEADS
    float* xg    = ald + (size_t)N_NODES * HEADS;                  // NB*CH
    float* y1    = xg + (size_t)NB * CH;                           // NB*NHID
    int* deg     = (int*)(y1 + (size_t)NB * NHID);                 // N
    int* rowptr  = deg + N_NODES;                                  // N
    int* cursor  = rowptr + N_NODES;                               // N
    int* bsum    = cursor + N_NODES;                               // <=64
    int* csr_src = bsum + 64;                                      // E2
    unsigned short* wt1h = (unsigned short*)(csr_src + E2_EDGES);  // 256*32
    unsigned short* wt1l = wt1h + 256 * 32;
    unsigned short* wt2h = wt1l + 256 * 32;                        // 256*256
    unsigned short* wt2l = wt2h + 256 * 256;
    unsigned short* wt3h = wt2l + 256 * 256;                       // 64*256
    unsigned short* wt3l = wt3h + 64 * 256;

    const int BLK = 256;
    const int NSCAN = cdiv(N_NODES, 1024);

    // ===================== fused prep (deg=0, x split, 3x W conv) ===========
    prep_kernel<<<cdiv(PREP_T4, BLK), BLK, 0, stream>>>(
        x, xh, xl, W1, wt1h, wt1l, W2, wt2h, wt2l, W3, wt3h, wt3l, deg);

    // ===================== CSR build (dst-sorted adjacency) ==================
    hist_kernel<<<cdiv(E2_EDGES, BLK), BLK, 0, stream>>>(ei, deg);
    scan_block_kernel<<<NSCAN, 256, 0, stream>>>(deg, rowptr, bsum);
    scan_bsum_kernel<<<1, 64, 0, stream>>>(bsum, NSCAN);
    finalize_rowptr_kernel<<<cdiv(N_NODES, BLK), BLK, 0, stream>>>(rowptr, bsum, cursor);
    scatter_kernel<<<cdiv(E2_EDGES, BLK), BLK, 0, stream>>>(ei, cursor, csr_src);

    // ===================== Layer 1 (F_IN -> H*C) =====================
    mfma_lin_fused_kernel<F_IN, HC, true><<<cdiv(N_NODES, 64), 256, 0, stream>>>(
        xh, xl, wt1h, wt1l, as1, ad1, bufH, als, ald, N_NODES);
    gat_agg_v3_kernel<<<N_NODES / 16, 256, 0, stream>>>(
        csr_src, rowptr, deg, bufH, als, ald, b1, aggh);

    // ===================== Layer 2 (H*C -> H*C) =====================
    mfma_lin_fused_kernel<HC, HC, false><<<cdiv(N_NODES, 64), 256, 0, stream>>>(
        aggh, nullptr, wt2h, wt2l, as2, ad2, bufH, als, ald, N_NODES);
    gat_agg_v3_kernel<<<N_NODES / 16, 256, 0, stream>>>(
        csr_src, rowptr, deg, bufH, als, ald, b2, aggh);

    // ===================== Layer 3 (H*C -> C, heads=1) =====================
    mfma_lin_fused_kernel<HC, CH, false><<<cdiv(N_NODES, 256), 256, 0, stream>>>(
        aggh, nullptr, wt3h, wt3l, as3, ad3, bufH, als, ald, N_NODES);
    gat_agg_h1_kernel<<<cdiv(N_NODES, 4), 256, 0, stream>>>(
        csr_src, rowptr, deg, bufH, als, ald, b3, bufO3, N_NODES);

    // ===================== Mean pooling (batch is sorted) =====================
    pool_kernel<<<NB, 64, 0, stream>>>(bufO3, batch, xg);

    // ===================== MLP head + LayerNorm =====================
    lin_kernel<CH, NHID, 16, 256, true><<<cdiv(NB, 16), 256, 0, stream>>>(
        xg, Wm1, bm1, y1, NB);
    mlp2_ln_kernel<<<NB, 256, 0, stream>>>(y1, Wm2, bm2, g2, be2, out);
}